// Round 1
// baseline (873.286 us; speedup 1.0000x reference)
//
#include <hip/hip_runtime.h>
#include <math.h>

#define B_   2
#define N_   2048
#define DIM_ 512
#define NH_  8
#define HD_  64
#define K_   32
#define PD_  16
#define TOK_ (B_*N_)     // 4096 rows
#define FFN_ 2048

// ---------------------------------------------------------------------------
// LayerNorm: one wave (64 lanes) per row of 512. 8 elems/lane.
// ---------------------------------------------------------------------------
__global__ void layernorm_kernel(const float* __restrict__ x,
                                 const float* __restrict__ scale,
                                 const float* __restrict__ bias,
                                 float* __restrict__ y)
{
    int wave = (blockIdx.x * blockDim.x + threadIdx.x) >> 6;
    int lane = threadIdx.x & 63;
    if (wave >= TOK_) return;
    const float* xr = x + (size_t)wave * DIM_;
    float v[8];
    float s = 0.f;
#pragma unroll
    for (int i = 0; i < 8; i++) { v[i] = xr[lane + i*64]; s += v[i]; }
#pragma unroll
    for (int off = 32; off; off >>= 1) s += __shfl_xor(s, off);
    float mean = s * (1.f / DIM_);
    float vs = 0.f;
#pragma unroll
    for (int i = 0; i < 8; i++) { float d = v[i] - mean; vs += d*d; }
#pragma unroll
    for (int off = 32; off; off >>= 1) vs += __shfl_xor(vs, off);
    float inv = rsqrtf(vs * (1.f / DIM_) + 1e-6f);
    float* yr = y + (size_t)wave * DIM_;
#pragma unroll
    for (int i = 0; i < 8; i++) {
        int c = lane + i*64;
        yr[c] = (v[i] - mean) * inv * scale[c] + bias[c];
    }
}

// ---------------------------------------------------------------------------
// fp32 tiled GEMM: C[M,N] = A[M,Kd] @ W[Kd,N] + bias (+res / gelu)
// 64x64 tile, 256 threads, 4x4 microtile, BK=16.
// EPI: 0 = +bias, 1 = +bias+residual, 2 = +bias, gelu(tanh approx)
// ---------------------------------------------------------------------------
__device__ __forceinline__ float gelu_tanh(float x) {
    float x3 = x * x * x;
    return 0.5f * x * (1.f + tanhf(0.7978845608028654f * (x + 0.044715f * x3)));
}

template<int EPI>
__global__ __launch_bounds__(256)
void gemm_kernel(const float* __restrict__ A, const float* __restrict__ W,
                 const float* __restrict__ bias, const float* __restrict__ res,
                 float* __restrict__ C, int M, int N, int Kd)
{
    __shared__ float As[64][17];   // padded: conflict-free row reads
    __shared__ float Bs[16][64];

    int t  = threadIdx.x;
    int tx = t & 15;      // 0..15 -> N microtiles
    int ty = t >> 4;      // 0..15 -> M microtiles
    int arow  = t >> 2;          // 0..63
    int acol4 = (t & 3) * 4;     // 0,4,8,12
    int brow  = t >> 4;          // 0..15
    int bcol4 = (t & 15) * 4;

    const float* Ab = A + (size_t)(blockIdx.y * 64) * Kd;
    const float* Wb = W + blockIdx.x * 64;

    float acc[4][4] = {};

    for (int k0 = 0; k0 < Kd; k0 += 16) {
        float4 av = *(const float4*)(Ab + (size_t)arow * Kd + k0 + acol4);
        float4 bv = *(const float4*)(Wb + (size_t)(k0 + brow) * N + bcol4);
        As[arow][acol4+0] = av.x;
        As[arow][acol4+1] = av.y;
        As[arow][acol4+2] = av.z;
        As[arow][acol4+3] = av.w;
        *(float4*)&Bs[brow][bcol4] = bv;
        __syncthreads();
#pragma unroll
        for (int kk = 0; kk < 16; kk++) {
            float a0 = As[ty*4+0][kk], a1 = As[ty*4+1][kk];
            float a2 = As[ty*4+2][kk], a3 = As[ty*4+3][kk];
            float b0 = Bs[kk][tx*4+0], b1 = Bs[kk][tx*4+1];
            float b2 = Bs[kk][tx*4+2], b3 = Bs[kk][tx*4+3];
            acc[0][0] += a0*b0; acc[0][1] += a0*b1; acc[0][2] += a0*b2; acc[0][3] += a0*b3;
            acc[1][0] += a1*b0; acc[1][1] += a1*b1; acc[1][2] += a1*b2; acc[1][3] += a1*b3;
            acc[2][0] += a2*b0; acc[2][1] += a2*b1; acc[2][2] += a2*b2; acc[2][3] += a2*b3;
            acc[3][0] += a3*b0; acc[3][1] += a3*b1; acc[3][2] += a3*b2; acc[3][3] += a3*b3;
        }
        __syncthreads();
    }

    int row0 = blockIdx.y * 64 + ty * 4;
    int col0 = blockIdx.x * 64 + tx * 4;
#pragma unroll
    for (int i = 0; i < 4; i++) {
#pragma unroll
        for (int j = 0; j < 4; j++) {
            int r = row0 + i, c = col0 + j;
            float val = acc[i][j] + bias[c];
            if (EPI == 1) val += res[(size_t)r * N + c];
            if (EPI == 2) val = gelu_tanh(val);
            C[(size_t)r * N + c] = val;
        }
    }
}

// ---------------------------------------------------------------------------
// positions squared norms
// ---------------------------------------------------------------------------
__global__ void pos_sq_kernel(const float* __restrict__ pos, float* __restrict__ pos_sq)
{
    int i = blockIdx.x * blockDim.x + threadIdx.x;
    if (i >= TOK_) return;
    const float* p = pos + (size_t)i * PD_;
    float s = 0.f;
#pragma unroll
    for (int d = 0; d < PD_; d++) s += p[d]*p[d];
    pos_sq[i] = s;
}

// ---------------------------------------------------------------------------
// Poincare dist row + exact top-K (iterative argmin, lower-index tie-break
// to match jax.lax.top_k). One block (256 thr) per (b,i).
// ---------------------------------------------------------------------------
__global__ __launch_bounds__(256)
void dist_topk_kernel(const float* __restrict__ pos, const float* __restrict__ pos_sq,
                      const float* __restrict__ c_ptr,
                      int* __restrict__ topk_idx, float* __restrict__ topk_dist)
{
    __shared__ float drow[N_];
    __shared__ float pi_s[PD_];
    __shared__ float red_v[256];
    __shared__ int   red_i[256];

    int bi = blockIdx.x;           // 0..B*N-1
    int b  = bi / N_;
    int t  = threadIdx.x;
    float c = *c_ptr;

    if (t < PD_) pi_s[t] = pos[(size_t)bi * PD_ + t];
    __syncthreads();

    float ni = pos_sq[bi];
    float inv_sqrt_c = rsqrtf(c);

    for (int j = t; j < N_; j += 256) {
        const float* pj = pos + ((size_t)b * N_ + j) * PD_;
        float diff = 0.f;
#pragma unroll
        for (int d = 0; d < PD_; d++) { float dd = pi_s[d] - pj[d]; diff += dd*dd; }
        float nj  = pos_sq[b * N_ + j];
        float den = fmaxf((1.f - c*ni) * (1.f - c*nj), 1e-8f);
        float arg = fmaxf(1.f + 2.f * c * diff / den, 1.f + 1e-7f);
        drow[j] = acoshf(arg) * inv_sqrt_c;
    }
    __syncthreads();

    for (int kk = 0; kk < K_; kk++) {
        float bv = INFINITY;
        int   bidx = 0x7fffffff;
        for (int j = t; j < N_; j += 256) {
            float vv = drow[j];
            if (vv < bv || (vv == bv && j < bidx)) { bv = vv; bidx = j; }
        }
        red_v[t] = bv; red_i[t] = bidx;
        __syncthreads();
        for (int s = 128; s > 0; s >>= 1) {
            if (t < s) {
                float ov = red_v[t+s]; int oi = red_i[t+s];
                if (ov < red_v[t] || (ov == red_v[t] && oi < red_i[t])) {
                    red_v[t] = ov; red_i[t] = oi;
                }
            }
            __syncthreads();
        }
        if (t == 0) {
            topk_idx[(size_t)bi * K_ + kk]  = red_i[0];
            topk_dist[(size_t)bi * K_ + kk] = red_v[0];
            drow[red_i[0]] = INFINITY;
        }
        __syncthreads();
    }
}

// ---------------------------------------------------------------------------
// Sparse attention: one wave per (b,h,i). Lane = d in [0,64).
// ---------------------------------------------------------------------------
__global__ __launch_bounds__(256)
void attn_kernel(const float* __restrict__ q, const float* __restrict__ k,
                 const float* __restrict__ v,
                 const int* __restrict__ topk_idx, const float* __restrict__ topk_dist,
                 const float* __restrict__ log_tau_p, const float* __restrict__ attn_scale_p,
                 float* __restrict__ out)
{
    int gw   = (blockIdx.x * blockDim.x + threadIdx.x) >> 6;
    int lane = threadIdx.x & 63;
    if (gw >= B_ * NH_ * N_) return;
    int b = gw / (NH_ * N_);
    int r = gw % (NH_ * N_);
    int h = r / N_;
    int i = r % N_;

    float tau    = fmaxf(expf(*log_tau_p), 1e-8f);
    float ascale = *attn_scale_p;

    size_t qbase = ((size_t)(b * N_ + i)) * DIM_ + h * HD_;
    float qd = q[qbase + lane];

    const int*   idxp = topk_idx  + (size_t)(b * N_ + i) * K_;
    const float* dstp = topk_dist + (size_t)(b * N_ + i) * K_;

    float sc[K_];
#pragma unroll
    for (int jj = 0; jj < K_; jj++) {
        int nb = idxp[jj];
        float kd = k[((size_t)(b * N_ + nb)) * DIM_ + h * HD_ + lane];
        float p = qd * kd;
#pragma unroll
        for (int off = 32; off; off >>= 1) p += __shfl_xor(p, off);
        float fs = p * 0.125f;                 // 1/sqrt(64)
        float gs = -dstp[jj] / tau;
        sc[jj] = ascale * tanhf(fs + gs);
    }
    float mx = sc[0];
#pragma unroll
    for (int jj = 1; jj < K_; jj++) mx = fmaxf(mx, sc[jj]);
    float se = 0.f;
#pragma unroll
    for (int jj = 0; jj < K_; jj++) { sc[jj] = expf(sc[jj] - mx); se += sc[jj]; }
    float inv = 1.f / se;
    float acc = 0.f;
#pragma unroll
    for (int jj = 0; jj < K_; jj++) {
        int nb = idxp[jj];
        acc += sc[jj] * inv * v[((size_t)(b * N_ + nb)) * DIM_ + h * HD_ + lane];
    }
    out[qbase + lane] = acc;
}

// ---------------------------------------------------------------------------
extern "C" void kernel_launch(void* const* d_in, const int* in_sizes, int n_in,
                              void* d_out, int out_size, void* d_ws, size_t ws_size,
                              hipStream_t stream)
{
    const float* x          = (const float*)d_in[0];
    const float* positions  = (const float*)d_in[1];
    const float* c_p        = (const float*)d_in[2];
    const float* Wq         = (const float*)d_in[3];
    const float* bq         = (const float*)d_in[4];
    const float* Wk         = (const float*)d_in[5];
    const float* bk         = (const float*)d_in[6];
    const float* Wv         = (const float*)d_in[7];
    const float* bv         = (const float*)d_in[8];
    const float* Wo         = (const float*)d_in[9];
    const float* bo         = (const float*)d_in[10];
    const float* W1         = (const float*)d_in[11];
    const float* b1         = (const float*)d_in[12];
    const float* W2         = (const float*)d_in[13];
    const float* b2         = (const float*)d_in[14];
    const float* ln1_scale  = (const float*)d_in[15];
    const float* ln1_bias   = (const float*)d_in[16];
    const float* ln2_scale  = (const float*)d_in[17];
    const float* ln2_bias   = (const float*)d_in[18];
    const float* log_tau    = (const float*)d_in[19];
    const float* attn_scale = (const float*)d_in[20];

    float* ws        = (float*)d_ws;
    float* xn        = ws;                         // 4096*512
    float* q         = xn  + (size_t)TOK_ * DIM_;
    float* k         = q   + (size_t)TOK_ * DIM_;
    float* v         = k   + (size_t)TOK_ * DIM_;
    float* attn_out  = v   + (size_t)TOK_ * DIM_;
    float* x1        = attn_out + (size_t)TOK_ * DIM_;
    float* x2n       = x1  + (size_t)TOK_ * DIM_;
    float* h_ffn     = x2n + (size_t)TOK_ * DIM_;  // 4096*2048
    float* pos_sq    = h_ffn + (size_t)TOK_ * FFN_;
    float* topk_dist = pos_sq + TOK_;
    int*   topk_idx  = (int*)(topk_dist + (size_t)TOK_ * K_);

    // LN1
    layernorm_kernel<<<TOK_/4, 256, 0, stream>>>(x, ln1_scale, ln1_bias, xn);

    // QKV projections
    dim3 g512(DIM_/64, TOK_/64);   // (8, 64)
    gemm_kernel<0><<<g512, 256, 0, stream>>>(xn, Wq, bq, nullptr, q, TOK_, DIM_, DIM_);
    gemm_kernel<0><<<g512, 256, 0, stream>>>(xn, Wk, bk, nullptr, k, TOK_, DIM_, DIM_);
    gemm_kernel<0><<<g512, 256, 0, stream>>>(xn, Wv, bv, nullptr, v, TOK_, DIM_, DIM_);

    // distances + top-k
    pos_sq_kernel<<<TOK_/256, 256, 0, stream>>>(positions, pos_sq);
    dist_topk_kernel<<<TOK_, 256, 0, stream>>>(positions, pos_sq, c_p, topk_idx, topk_dist);

    // sparse attention
    attn_kernel<<<(B_*NH_*N_)/4, 256, 0, stream>>>(q, k, v, topk_idx, topk_dist,
                                                   log_tau, attn_scale, attn_out);

    // x1 = x + attn_out @ Wo + bo
    gemm_kernel<1><<<g512, 256, 0, stream>>>(attn_out, Wo, bo, x, x1, TOK_, DIM_, DIM_);

    // LN2
    layernorm_kernel<<<TOK_/4, 256, 0, stream>>>(x1, ln2_scale, ln2_bias, x2n);

    // FFN
    dim3 gffn(FFN_/64, TOK_/64);   // (32, 64)
    gemm_kernel<2><<<gffn, 256, 0, stream>>>(x2n, W1, b1, nullptr, h_ffn, TOK_, FFN_, DIM_);
    gemm_kernel<1><<<g512, 256, 0, stream>>>(h_ffn, W2, b2, x1, (float*)d_out, TOK_, DIM_, FFN_);
}

// Round 2
// 491.672 us; speedup vs baseline: 1.7762x; 1.7762x over previous
//
#include <hip/hip_runtime.h>
#include <math.h>

#define B_   2
#define N_   2048
#define DIM_ 512
#define NH_  8
#define HD_  64
#define K_   32
#define PD_  16
#define TOK_ (B_*N_)     // 4096 rows
#define FFN_ 2048
#define QKV_ (3*DIM_)    // 1536

typedef __bf16 bf16x8 __attribute__((ext_vector_type(8)));
typedef float  f32x4  __attribute__((ext_vector_type(4)));

__device__ __forceinline__ unsigned short f2bf(float f) {
    unsigned int u = __float_as_uint(f);
    u = (u + 0x7fffu + ((u >> 16) & 1u)) >> 16;
    return (unsigned short)u;
}

__device__ __forceinline__ float gelu_tanh(float x) {
    float x3 = x * x * x;
    return 0.5f * x * (1.f + tanhf(0.7978845608028654f * (x + 0.044715f * x3)));
}

// async global->LDS, 16B per lane. LDS dst must be wave-uniform base + lane*16.
#define GLOAD_LDS16(g, l) __builtin_amdgcn_global_load_lds(                        \
    (const __attribute__((address_space(1))) unsigned int*)(const void*)(g),       \
    (__attribute__((address_space(3))) unsigned int*)(void*)(l), 16, 0, 0)

// ---------------------------------------------------------------------------
// LayerNorm: one wave per row of 512; writes bf16.
// ---------------------------------------------------------------------------
__global__ void layernorm_kernel(const float* __restrict__ x,
                                 const float* __restrict__ scale,
                                 const float* __restrict__ bias,
                                 unsigned short* __restrict__ y)
{
    int wave = (blockIdx.x * blockDim.x + threadIdx.x) >> 6;
    int lane = threadIdx.x & 63;
    if (wave >= TOK_) return;
    const float* xr = x + (size_t)wave * DIM_;
    float v[8];
    float s = 0.f;
#pragma unroll
    for (int i = 0; i < 8; i++) { v[i] = xr[lane + i*64]; s += v[i]; }
#pragma unroll
    for (int off = 32; off; off >>= 1) s += __shfl_xor(s, off);
    float mean = s * (1.f / DIM_);
    float vs = 0.f;
#pragma unroll
    for (int i = 0; i < 8; i++) { float d = v[i] - mean; vs += d*d; }
#pragma unroll
    for (int off = 32; off; off >>= 1) vs += __shfl_xor(vs, off);
    float inv = rsqrtf(vs * (1.f / DIM_) + 1e-6f);
    unsigned short* yr = y + (size_t)wave * DIM_;
#pragma unroll
    for (int i = 0; i < 8; i++) {
        int c = lane + i*64;
        yr[c] = f2bf((v[i] - mean) * inv * scale[c] + bias[c]);
    }
}

// ---------------------------------------------------------------------------
// Transpose + cast: Wt[n][k] = bf16(W[k][n]).  32x32 LDS tile, 256 threads.
// ---------------------------------------------------------------------------
__global__ void transpose_cast_kernel(const float* __restrict__ W,
                                      unsigned short* __restrict__ Wt,
                                      int Kd, int Nw)
{
    __shared__ float tile[32][33];
    int n0 = blockIdx.x * 32, k0 = blockIdx.y * 32;
    int tx = threadIdx.x & 31, ty = threadIdx.x >> 5;   // ty in 0..7
#pragma unroll
    for (int i = 0; i < 32; i += 8)
        tile[ty + i][tx] = W[(size_t)(k0 + ty + i) * Nw + n0 + tx];
    __syncthreads();
#pragma unroll
    for (int i = 0; i < 32; i += 8)
        Wt[(size_t)(n0 + ty + i) * Kd + k0 + tx] = f2bf(tile[tx][ty + i]);
}

__global__ void pack_bias3_kernel(const float* __restrict__ a, const float* __restrict__ b,
                                  const float* __restrict__ c, float* __restrict__ o)
{
    int i = blockIdx.x * 256 + threadIdx.x;
    if (i < DIM_)            o[i] = a[i];
    else if (i < 2*DIM_)     o[i] = b[i - DIM_];
    else if (i < 3*DIM_)     o[i] = c[i - 2*DIM_];
}

// ---------------------------------------------------------------------------
// bf16 MFMA GEMM: C[M,N] = A[M,Kd] @ Bt[N,Kd]^T (+bias / +res / gelu)
// 128x128 tile, BK=32, 256 threads (4 waves 2x2), 16x16x32 bf16 MFMA.
// EPI: 0 = +bias -> fp32 ; 1 = +bias+res -> fp32 ; 2 = gelu(+bias) -> bf16
// ---------------------------------------------------------------------------
template<int EPI>
__global__ __launch_bounds__(256)
void gemm_bf16_kernel(const unsigned short* __restrict__ A,
                      const unsigned short* __restrict__ Bt,
                      const float* __restrict__ bias,
                      const float* __restrict__ res,
                      float* __restrict__ Cf,
                      unsigned short* __restrict__ Cb,
                      int M, int N, int Kd)
{
    __shared__ unsigned short As[128*32];   // 8 KB
    __shared__ unsigned short Bs[128*32];   // 8 KB

    int t    = threadIdx.x;
    int lane = t & 63;
    int wid  = t >> 6;
    int wm   = wid >> 1, wn = wid & 1;

    int bm0 = blockIdx.y * 128;
    int bn0 = blockIdx.x * 128;

    int srow = t >> 2;          // 0..63
    int scol = (t & 3) * 8;     // 0,8,16,24

    const unsigned short* gA0 = A  + (size_t)(bm0 + srow)      * Kd + scol;
    const unsigned short* gA1 = A  + (size_t)(bm0 + 64 + srow) * Kd + scol;
    const unsigned short* gB0 = Bt + (size_t)(bn0 + srow)      * Kd + scol;
    const unsigned short* gB1 = Bt + (size_t)(bn0 + 64 + srow) * Kd + scol;

    unsigned short* lA0 = As + t*8;          // == (srow*32 + scol)
    unsigned short* lA1 = As + 2048 + t*8;
    unsigned short* lB0 = Bs + t*8;
    unsigned short* lB1 = Bs + 2048 + t*8;

    f32x4 acc[4][4] = {};

    int arow = wm*64 + (lane & 15);       // + mi*16
    int brow = wn*64 + (lane & 15);       // + ni*16
    int kfrag = (lane >> 4) * 8;

    for (int k0 = 0; k0 < Kd; k0 += 32) {
        GLOAD_LDS16(gA0 + k0, lA0);
        GLOAD_LDS16(gA1 + k0, lA1);
        GLOAD_LDS16(gB0 + k0, lB0);
        GLOAD_LDS16(gB1 + k0, lB1);
        __syncthreads();

        bf16x8 af[4], bf[4];
#pragma unroll
        for (int mi = 0; mi < 4; mi++)
            af[mi] = *(const bf16x8*)(As + (arow + mi*16)*32 + kfrag);
#pragma unroll
        for (int ni = 0; ni < 4; ni++)
            bf[ni] = *(const bf16x8*)(Bs + (brow + ni*16)*32 + kfrag);
#pragma unroll
        for (int mi = 0; mi < 4; mi++)
#pragma unroll
            for (int ni = 0; ni < 4; ni++)
                acc[mi][ni] = __builtin_amdgcn_mfma_f32_16x16x32_bf16(
                    af[mi], bf[ni], acc[mi][ni], 0, 0, 0);
        __syncthreads();
    }

    // epilogue: D row = (lane>>4)*4 + r, col = lane&15 within each 16x16 tile
#pragma unroll
    for (int mi = 0; mi < 4; mi++) {
#pragma unroll
        for (int ni = 0; ni < 4; ni++) {
            int col = bn0 + wn*64 + ni*16 + (lane & 15);
            float bv = bias[col];
#pragma unroll
            for (int r = 0; r < 4; r++) {
                int row = bm0 + wm*64 + mi*16 + (lane >> 4)*4 + r;
                float val = acc[mi][ni][r] + bv;
                if (EPI == 1) val += res[(size_t)row * N + col];
                if (EPI == 2) {
                    val = gelu_tanh(val);
                    Cb[(size_t)row * N + col] = f2bf(val);
                } else {
                    Cf[(size_t)row * N + col] = val;
                }
            }
        }
    }
}

// ---------------------------------------------------------------------------
// positions squared norms
// ---------------------------------------------------------------------------
__global__ void pos_sq_kernel(const float* __restrict__ pos, float* __restrict__ pos_sq)
{
    int i = blockIdx.x * blockDim.x + threadIdx.x;
    if (i >= TOK_) return;
    const float4* p = (const float4*)(pos + (size_t)i * PD_);
    float s = 0.f;
#pragma unroll
    for (int d = 0; d < 4; d++) {
        float4 q = p[d];
        s += q.x*q.x + q.y*q.y + q.z*q.z + q.w*q.w;
    }
    pos_sq[i] = s;
}

// ---------------------------------------------------------------------------
// Poincare dist + exact top-K: ONE WAVE per row. 2048 dists in regs (32/lane),
// 32 iterations of packed-key (dist_bits<<32 | idx) wave-min. No LDS, no
// __syncthreads. Tie-break = lower index (matches jax.lax.top_k).
// ---------------------------------------------------------------------------
__global__ __launch_bounds__(256)
void dist_topk_wave_kernel(const float* __restrict__ pos, const float* __restrict__ pos_sq,
                           const float* __restrict__ c_ptr,
                           int* __restrict__ topk_idx, float* __restrict__ topk_dist)
{
    int wid  = threadIdx.x >> 6;
    int lane = threadIdx.x & 63;
    int bi   = blockIdx.x * 4 + wid;      // 0..TOK_-1
    int b    = bi >> 11;                  // / N_
    float c  = *c_ptr;
    float inv_sqrt_c = rsqrtf(c);

    const float4* pi4 = (const float4*)(pos + (size_t)bi * PD_);
    float4 p0 = pi4[0], p1 = pi4[1], p2 = pi4[2], p3 = pi4[3];
    float ni = pos_sq[bi];
    float omci = 1.f - c * ni;

    const float* pb = pos + (size_t)b * N_ * PD_;
    const float* sqb = pos_sq + b * N_;

    float d[32];
#pragma unroll
    for (int tt = 0; tt < 32; tt++) {
        int j = tt*64 + lane;
        const float4* pj = (const float4*)(pb + (size_t)j * PD_);
        float4 q0 = pj[0], q1 = pj[1], q2 = pj[2], q3 = pj[3];
        float diff =
            (p0.x-q0.x)*(p0.x-q0.x) + (p0.y-q0.y)*(p0.y-q0.y) +
            (p0.z-q0.z)*(p0.z-q0.z) + (p0.w-q0.w)*(p0.w-q0.w) +
            (p1.x-q1.x)*(p1.x-q1.x) + (p1.y-q1.y)*(p1.y-q1.y) +
            (p1.z-q1.z)*(p1.z-q1.z) + (p1.w-q1.w)*(p1.w-q1.w) +
            (p2.x-q2.x)*(p2.x-q2.x) + (p2.y-q2.y)*(p2.y-q2.y) +
            (p2.z-q2.z)*(p2.z-q2.z) + (p2.w-q2.w)*(p2.w-q2.w) +
            (p3.x-q3.x)*(p3.x-q3.x) + (p3.y-q3.y)*(p3.y-q3.y) +
            (p3.z-q3.z)*(p3.z-q3.z) + (p3.w-q3.w)*(p3.w-q3.w);
        float den = fmaxf(omci * (1.f - c * sqb[j]), 1e-8f);
        float arg = fmaxf(1.f + 2.f * c * diff / den, 1.f + 1e-7f);
        d[tt] = acoshf(arg) * inv_sqrt_c;
    }

    int   out_i = 0;
    float out_d = 0.f;
#pragma unroll 1
    for (int kk = 0; kk < K_; kk++) {
        unsigned long long best = 0xffffffffffffffffULL;
#pragma unroll
        for (int tt = 0; tt < 32; tt++) {
            unsigned long long key =
                ((unsigned long long)__float_as_uint(d[tt]) << 32) | (unsigned)(tt*64 + lane);
            best = best < key ? best : key;
        }
#pragma unroll
        for (int off = 32; off; off >>= 1) {
            unsigned long long o = __shfl_xor(best, off);
            best = best < o ? best : o;
        }
        int   wj = (int)(best & 0xffffffffu);
        float wd = __uint_as_float((unsigned)(best >> 32));
        if (lane == kk) { out_i = wj; out_d = wd; }
#pragma unroll
        for (int tt = 0; tt < 32; tt++)
            if (tt*64 + lane == wj) d[tt] = INFINITY;
    }
    if (lane < K_) {
        topk_idx [(size_t)bi * K_ + lane] = out_i;
        topk_dist[(size_t)bi * K_ + lane] = out_d;
    }
}

// ---------------------------------------------------------------------------
// Sparse attention: one wave per (b,h,i). Lane = d. qkv fp32 [tok][1536].
// Writes bf16 attn_out [tok][512].
// ---------------------------------------------------------------------------
__global__ __launch_bounds__(256)
void attn_kernel(const float* __restrict__ qkv,
                 const int* __restrict__ topk_idx, const float* __restrict__ topk_dist,
                 const float* __restrict__ log_tau_p, const float* __restrict__ attn_scale_p,
                 unsigned short* __restrict__ out)
{
    int gw   = (blockIdx.x * blockDim.x + threadIdx.x) >> 6;
    int lane = threadIdx.x & 63;
    if (gw >= B_ * NH_ * N_) return;
    int b = gw / (NH_ * N_);
    int r = gw % (NH_ * N_);
    int h = r / N_;
    int i = r % N_;
    int tok = b * N_ + i;

    float tau    = fmaxf(expf(*log_tau_p), 1e-8f);
    float ascale = *attn_scale_p;

    float qd = qkv[(size_t)tok * QKV_ + h * HD_ + lane];

    const int*   idxp = topk_idx  + (size_t)tok * K_;
    const float* dstp = topk_dist + (size_t)tok * K_;

    float sc[K_];
#pragma unroll
    for (int jj = 0; jj < K_; jj++) {
        int nb = idxp[jj];
        float kd = qkv[(size_t)(b * N_ + nb) * QKV_ + DIM_ + h * HD_ + lane];
        float p = qd * kd;
#pragma unroll
        for (int off = 32; off; off >>= 1) p += __shfl_xor(p, off);
        float fs = p * 0.125f;                 // 1/sqrt(64)
        float gs = -dstp[jj] / tau;
        sc[jj] = ascale * tanhf(fs + gs);
    }
    float mx = sc[0];
#pragma unroll
    for (int jj = 1; jj < K_; jj++) mx = fmaxf(mx, sc[jj]);
    float se = 0.f;
#pragma unroll
    for (int jj = 0; jj < K_; jj++) { sc[jj] = expf(sc[jj] - mx); se += sc[jj]; }
    float inv = 1.f / se;
    float acc = 0.f;
#pragma unroll
    for (int jj = 0; jj < K_; jj++) {
        int nb = idxp[jj];
        acc += sc[jj] * inv * qkv[(size_t)(b * N_ + nb) * QKV_ + 2*DIM_ + h * HD_ + lane];
    }
    out[(size_t)tok * DIM_ + h * HD_ + lane] = f2bf(acc);
}

// ---------------------------------------------------------------------------
extern "C" void kernel_launch(void* const* d_in, const int* in_sizes, int n_in,
                              void* d_out, int out_size, void* d_ws, size_t ws_size,
                              hipStream_t stream)
{
    const float* x          = (const float*)d_in[0];
    const float* positions  = (const float*)d_in[1];
    const float* c_p        = (const float*)d_in[2];
    const float* Wq         = (const float*)d_in[3];
    const float* bq         = (const float*)d_in[4];
    const float* Wk         = (const float*)d_in[5];
    const float* bk         = (const float*)d_in[6];
    const float* Wv         = (const float*)d_in[7];
    const float* bv         = (const float*)d_in[8];
    const float* Wo         = (const float*)d_in[9];
    const float* bo         = (const float*)d_in[10];
    const float* W1         = (const float*)d_in[11];
    const float* b1         = (const float*)d_in[12];
    const float* W2         = (const float*)d_in[13];
    const float* b2         = (const float*)d_in[14];
    const float* ln1_scale  = (const float*)d_in[15];
    const float* ln1_bias   = (const float*)d_in[16];
    const float* ln2_scale  = (const float*)d_in[17];
    const float* ln2_bias   = (const float*)d_in[18];
    const float* log_tau    = (const float*)d_in[19];
    const float* attn_scale = (const float*)d_in[20];

    char* p = (char*)d_ws;
    unsigned short* qkvWt  = (unsigned short*)p; p += (size_t)QKV_ * DIM_ * 2;   // [1536][512] bf16
    unsigned short* WoT    = (unsigned short*)p; p += (size_t)DIM_ * DIM_ * 2;   // [512][512]
    unsigned short* W1T    = (unsigned short*)p; p += (size_t)FFN_ * DIM_ * 2;   // [2048][512]
    unsigned short* W2T    = (unsigned short*)p; p += (size_t)DIM_ * FFN_ * 2;   // [512][2048]
    float*          qkv_b  = (float*)p;          p += (size_t)QKV_ * 4;
    unsigned short* xn     = (unsigned short*)p; p += (size_t)TOK_ * DIM_ * 2;   // bf16
    float*          qkv    = (float*)p;          p += (size_t)TOK_ * QKV_ * 4;   // fp32
    unsigned short* attn_o = (unsigned short*)p; p += (size_t)TOK_ * DIM_ * 2;   // bf16
    float*          x1     = (float*)p;          p += (size_t)TOK_ * DIM_ * 4;
    unsigned short* x2n    = (unsigned short*)p; p += (size_t)TOK_ * DIM_ * 2;
    unsigned short* hbuf   = (unsigned short*)p; p += (size_t)TOK_ * FFN_ * 2;
    float*          pos_sq = (float*)p;          p += (size_t)TOK_ * 4;
    float*          tk_d   = (float*)p;          p += (size_t)TOK_ * K_ * 4;
    int*            tk_i   = (int*)p;            p += (size_t)TOK_ * K_ * 4;

    // --- weight prep (runs every call; weights are restored each launch) ---
    dim3 tc512(DIM_/32, DIM_/32);     // 16x16
    transpose_cast_kernel<<<tc512, 256, 0, stream>>>(Wq, qkvWt,                 DIM_, DIM_);
    transpose_cast_kernel<<<tc512, 256, 0, stream>>>(Wk, qkvWt + DIM_*DIM_,     DIM_, DIM_);
    transpose_cast_kernel<<<tc512, 256, 0, stream>>>(Wv, qkvWt + 2*DIM_*DIM_,   DIM_, DIM_);
    transpose_cast_kernel<<<tc512, 256, 0, stream>>>(Wo, WoT,                   DIM_, DIM_);
    transpose_cast_kernel<<<dim3(FFN_/32, DIM_/32), 256, 0, stream>>>(W1, W1T,  DIM_, FFN_);
    transpose_cast_kernel<<<dim3(DIM_/32, FFN_/32), 256, 0, stream>>>(W2, W2T,  FFN_, DIM_);
    pack_bias3_kernel<<<QKV_/256, 256, 0, stream>>>(bq, bk, bv, qkv_b);

    // --- LN1 -> bf16 ---
    layernorm_kernel<<<TOK_/4, 256, 0, stream>>>(x, ln1_scale, ln1_bias, xn);

    // --- fused QKV GEMM: [4096,512] @ [512,1536] -> fp32 qkv ---
    gemm_bf16_kernel<0><<<dim3(QKV_/128, TOK_/128), 256, 0, stream>>>(
        xn, qkvWt, qkv_b, nullptr, qkv, nullptr, TOK_, QKV_, DIM_);

    // --- distances + top-k ---
    pos_sq_kernel<<<TOK_/256, 256, 0, stream>>>(positions, pos_sq);
    dist_topk_wave_kernel<<<TOK_/4, 256, 0, stream>>>(positions, pos_sq, c_p, tk_i, tk_d);

    // --- sparse attention -> bf16 ---
    attn_kernel<<<(B_*NH_*N_)/4, 256, 0, stream>>>(qkv, tk_i, tk_d, log_tau, attn_scale, attn_o);

    // --- x1 = x + attn_o @ Wo + bo (fp32) ---
    gemm_bf16_kernel<1><<<dim3(DIM_/128, TOK_/128), 256, 0, stream>>>(
        attn_o, WoT, bo, x, x1, nullptr, TOK_, DIM_, DIM_);

    // --- LN2 -> bf16 ---
    layernorm_kernel<<<TOK_/4, 256, 0, stream>>>(x1, ln2_scale, ln2_bias, x2n);

    // --- FFN1: gelu(x2n @ W1 + b1) -> bf16 h ---
    gemm_bf16_kernel<2><<<dim3(FFN_/128, TOK_/128), 256, 0, stream>>>(
        x2n, W1T, b1, nullptr, nullptr, hbuf, TOK_, FFN_, DIM_);

    // --- FFN2: out = x1 + h @ W2 + b2 (fp32) ---
    gemm_bf16_kernel<1><<<dim3(DIM_/128, TOK_/128), 256, 0, stream>>>(
        hbuf, W2T, b2, x1, (float*)d_out, nullptr, TOK_, DIM_, FFN_);
}

// Round 3
// 383.389 us; speedup vs baseline: 2.2778x; 1.2824x over previous
//
#include <hip/hip_runtime.h>
#include <math.h>

#define B_   2
#define N_   2048
#define DIM_ 512
#define NH_  8
#define HD_  64
#define K_   32
#define PD_  16
#define TOK_ (B_*N_)     // 4096 rows
#define FFN_ 2048
#define QKV_ (3*DIM_)    // 1536

typedef __bf16 bf16x8 __attribute__((ext_vector_type(8)));
typedef float  f32x4  __attribute__((ext_vector_type(4)));

__device__ __forceinline__ unsigned short f2bf(float f) {
    unsigned int u = __float_as_uint(f);
    u = (u + 0x7fffu + ((u >> 16) & 1u)) >> 16;
    return (unsigned short)u;
}

__device__ __forceinline__ float gelu_tanh(float x) {
    float x3 = x * x * x;
    return 0.5f * x * (1.f + tanhf(0.7978845608028654f * (x + 0.044715f * x3)));
}

__device__ __forceinline__ float tanh_fast(float x) {
    // tanh(x) = 1 - 2/(exp(2x)+1); exact at both saturation ends
    float e = __expf(2.f * x);
    return 1.f - 2.f / (e + 1.f);
}

// async global->LDS, 16B per lane. LDS dst must be wave-uniform base + lane*16.
#define GLOAD_LDS16(g, l) __builtin_amdgcn_global_load_lds(                        \
    (const __attribute__((address_space(1))) unsigned int*)(const void*)(g),       \
    (__attribute__((address_space(3))) unsigned int*)(void*)(l), 16, 0, 0)

// ---------------------------------------------------------------------------
// LayerNorm: one wave per row of 512; writes bf16.
// ---------------------------------------------------------------------------
__global__ void layernorm_kernel(const float* __restrict__ x,
                                 const float* __restrict__ scale,
                                 const float* __restrict__ bias,
                                 unsigned short* __restrict__ y)
{
    int wave = (blockIdx.x * blockDim.x + threadIdx.x) >> 6;
    int lane = threadIdx.x & 63;
    if (wave >= TOK_) return;
    const float* xr = x + (size_t)wave * DIM_;
    float v[8];
    float s = 0.f;
#pragma unroll
    for (int i = 0; i < 8; i++) { v[i] = xr[lane + i*64]; s += v[i]; }
#pragma unroll
    for (int off = 32; off; off >>= 1) s += __shfl_xor(s, off);
    float mean = s * (1.f / DIM_);
    float vs = 0.f;
#pragma unroll
    for (int i = 0; i < 8; i++) { float d = v[i] - mean; vs += d*d; }
#pragma unroll
    for (int off = 32; off; off >>= 1) vs += __shfl_xor(vs, off);
    float inv = rsqrtf(vs * (1.f / DIM_) + 1e-6f);
    unsigned short* yr = y + (size_t)wave * DIM_;
#pragma unroll
    for (int i = 0; i < 8; i++) {
        int c = lane + i*64;
        yr[c] = f2bf((v[i] - mean) * inv * scale[c] + bias[c]);
    }
}

// ---------------------------------------------------------------------------
// Transpose + cast: Wt[n][k] = bf16(W[k][n]).  32x32 LDS tile, 256 threads.
// ---------------------------------------------------------------------------
__global__ void transpose_cast_kernel(const float* __restrict__ W,
                                      unsigned short* __restrict__ Wt,
                                      int Kd, int Nw)
{
    __shared__ float tile[32][33];
    int n0 = blockIdx.x * 32, k0 = blockIdx.y * 32;
    int tx = threadIdx.x & 31, ty = threadIdx.x >> 5;   // ty in 0..7
#pragma unroll
    for (int i = 0; i < 32; i += 8)
        tile[ty + i][tx] = W[(size_t)(k0 + ty + i) * Nw + n0 + tx];
    __syncthreads();
#pragma unroll
    for (int i = 0; i < 32; i += 8)
        Wt[(size_t)(n0 + ty + i) * Kd + k0 + tx] = f2bf(tile[tx][ty + i]);
}

__global__ void pack_bias3_kernel(const float* __restrict__ a, const float* __restrict__ b,
                                  const float* __restrict__ c, float* __restrict__ o)
{
    int i = blockIdx.x * 256 + threadIdx.x;
    if (i < DIM_)            o[i] = a[i];
    else if (i < 2*DIM_)     o[i] = b[i - DIM_];
    else if (i < 3*DIM_)     o[i] = c[i - 2*DIM_];
}

// ---------------------------------------------------------------------------
// bf16 MFMA GEMM: C[M,N] = A[M,Kd] @ Bt[N,Kd]^T (+bias / +res / gelu)
// 128x128 tile, BK=32, 256 threads (4 waves 2x2), 16x16x32 bf16 MFMA.
// EPI: 0 = +bias -> fp32 ; 1 = +bias+res -> fp32 ; 2 = gelu(+bias) -> bf16
// ---------------------------------------------------------------------------
template<int EPI>
__global__ __launch_bounds__(256)
void gemm_bf16_kernel(const unsigned short* __restrict__ A,
                      const unsigned short* __restrict__ Bt,
                      const float* __restrict__ bias,
                      const float* __restrict__ res,
                      float* __restrict__ Cf,
                      unsigned short* __restrict__ Cb,
                      int M, int N, int Kd)
{
    __shared__ unsigned short As[128*32];   // 8 KB
    __shared__ unsigned short Bs[128*32];   // 8 KB

    int t    = threadIdx.x;
    int lane = t & 63;
    int wid  = t >> 6;
    int wm   = wid >> 1, wn = wid & 1;

    int bm0 = blockIdx.y * 128;
    int bn0 = blockIdx.x * 128;

    int srow = t >> 2;          // 0..63
    int scol = (t & 3) * 8;     // 0,8,16,24

    const unsigned short* gA0 = A  + (size_t)(bm0 + srow)      * Kd + scol;
    const unsigned short* gA1 = A  + (size_t)(bm0 + 64 + srow) * Kd + scol;
    const unsigned short* gB0 = Bt + (size_t)(bn0 + srow)      * Kd + scol;
    const unsigned short* gB1 = Bt + (size_t)(bn0 + 64 + srow) * Kd + scol;

    unsigned short* lA0 = As + t*8;          // == (srow*32 + scol)
    unsigned short* lA1 = As + 2048 + t*8;
    unsigned short* lB0 = Bs + t*8;
    unsigned short* lB1 = Bs + 2048 + t*8;

    f32x4 acc[4][4] = {};

    int arow = wm*64 + (lane & 15);       // + mi*16
    int brow = wn*64 + (lane & 15);       // + ni*16
    int kfrag = (lane >> 4) * 8;

    for (int k0 = 0; k0 < Kd; k0 += 32) {
        GLOAD_LDS16(gA0 + k0, lA0);
        GLOAD_LDS16(gA1 + k0, lA1);
        GLOAD_LDS16(gB0 + k0, lB0);
        GLOAD_LDS16(gB1 + k0, lB1);
        __syncthreads();

        bf16x8 af[4], bf[4];
#pragma unroll
        for (int mi = 0; mi < 4; mi++)
            af[mi] = *(const bf16x8*)(As + (arow + mi*16)*32 + kfrag);
#pragma unroll
        for (int ni = 0; ni < 4; ni++)
            bf[ni] = *(const bf16x8*)(Bs + (brow + ni*16)*32 + kfrag);
#pragma unroll
        for (int mi = 0; mi < 4; mi++)
#pragma unroll
            for (int ni = 0; ni < 4; ni++)
                acc[mi][ni] = __builtin_amdgcn_mfma_f32_16x16x32_bf16(
                    af[mi], bf[ni], acc[mi][ni], 0, 0, 0);
        __syncthreads();
    }

    // epilogue: D row = (lane>>4)*4 + r, col = lane&15 within each 16x16 tile
#pragma unroll
    for (int mi = 0; mi < 4; mi++) {
#pragma unroll
        for (int ni = 0; ni < 4; ni++) {
            int col = bn0 + wn*64 + ni*16 + (lane & 15);
            float bv = bias[col];
#pragma unroll
            for (int r = 0; r < 4; r++) {
                int row = bm0 + wm*64 + mi*16 + (lane >> 4)*4 + r;
                float val = acc[mi][ni][r] + bv;
                if (EPI == 1) val += res[(size_t)row * N + col];
                if (EPI == 2) {
                    val = gelu_tanh(val);
                    Cb[(size_t)row * N + col] = f2bf(val);
                } else {
                    Cf[(size_t)row * N + col] = val;
                }
            }
        }
    }
}

// ---------------------------------------------------------------------------
// positions squared norms
// ---------------------------------------------------------------------------
__global__ void pos_sq_kernel(const float* __restrict__ pos, float* __restrict__ pos_sq)
{
    int i = blockIdx.x * blockDim.x + threadIdx.x;
    if (i >= TOK_) return;
    const float4* p = (const float4*)(pos + (size_t)i * PD_);
    float s = 0.f;
#pragma unroll
    for (int d = 0; d < 4; d++) {
        float4 q = p[d];
        s += q.x*q.x + q.y*q.y + q.z*q.z + q.w*q.w;
    }
    pos_sq[i] = s;
}

// ---------------------------------------------------------------------------
// Poincare dist + exact top-K: ONE WAVE per row. 2048 dists in regs (32/lane),
// 32 iterations of packed-key (dist_bits<<32 | idx) wave-min. No LDS, no
// __syncthreads. Tie-break = lower index (matches jax.lax.top_k).
// ---------------------------------------------------------------------------
__global__ __launch_bounds__(256)
void dist_topk_wave_kernel(const float* __restrict__ pos, const float* __restrict__ pos_sq,
                           const float* __restrict__ c_ptr,
                           int* __restrict__ topk_idx, float* __restrict__ topk_dist)
{
    int wid  = threadIdx.x >> 6;
    int lane = threadIdx.x & 63;
    int bi   = blockIdx.x * 4 + wid;      // 0..TOK_-1
    int b    = bi >> 11;                  // / N_
    float c  = *c_ptr;
    float inv_sqrt_c = rsqrtf(c);

    const float4* pi4 = (const float4*)(pos + (size_t)bi * PD_);
    float4 p0 = pi4[0], p1 = pi4[1], p2 = pi4[2], p3 = pi4[3];
    float ni = pos_sq[bi];
    float omci = 1.f - c * ni;

    const float* pb = pos + (size_t)b * N_ * PD_;
    const float* sqb = pos_sq + b * N_;

    float d[32];
#pragma unroll
    for (int tt = 0; tt < 32; tt++) {
        int j = tt*64 + lane;
        const float4* pj = (const float4*)(pb + (size_t)j * PD_);
        float4 q0 = pj[0], q1 = pj[1], q2 = pj[2], q3 = pj[3];
        float diff =
            (p0.x-q0.x)*(p0.x-q0.x) + (p0.y-q0.y)*(p0.y-q0.y) +
            (p0.z-q0.z)*(p0.z-q0.z) + (p0.w-q0.w)*(p0.w-q0.w) +
            (p1.x-q1.x)*(p1.x-q1.x) + (p1.y-q1.y)*(p1.y-q1.y) +
            (p1.z-q1.z)*(p1.z-q1.z) + (p1.w-q1.w)*(p1.w-q1.w) +
            (p2.x-q2.x)*(p2.x-q2.x) + (p2.y-q2.y)*(p2.y-q2.y) +
            (p2.z-q2.z)*(p2.z-q2.z) + (p2.w-q2.w)*(p2.w-q2.w) +
            (p3.x-q3.x)*(p3.x-q3.x) + (p3.y-q3.y)*(p3.y-q3.y) +
            (p3.z-q3.z)*(p3.z-q3.z) + (p3.w-q3.w)*(p3.w-q3.w);
        float den = fmaxf(omci * (1.f - c * sqb[j]), 1e-8f);
        float arg = fmaxf(1.f + 2.f * c * diff / den, 1.f + 1e-7f);
        d[tt] = acoshf(arg) * inv_sqrt_c;
    }

    int   out_i = 0;
    float out_d = 0.f;
#pragma unroll 1
    for (int kk = 0; kk < K_; kk++) {
        unsigned long long best = 0xffffffffffffffffULL;
#pragma unroll
        for (int tt = 0; tt < 32; tt++) {
            unsigned long long key =
                ((unsigned long long)__float_as_uint(d[tt]) << 32) | (unsigned)(tt*64 + lane);
            best = best < key ? best : key;
        }
#pragma unroll
        for (int off = 32; off; off >>= 1) {
            unsigned long long o = __shfl_xor(best, off);
            best = best < o ? best : o;
        }
        int   wj = (int)(best & 0xffffffffu);
        float wd = __uint_as_float((unsigned)(best >> 32));
        if (lane == kk) { out_i = wj; out_d = wd; }
#pragma unroll
        for (int tt = 0; tt < 32; tt++)
            if (tt*64 + lane == wj) d[tt] = INFINITY;
    }
    if (lane < K_) {
        topk_idx [(size_t)bi * K_ + lane] = out_i;
        topk_dist[(size_t)bi * K_ + lane] = out_d;
    }
}

// ---------------------------------------------------------------------------
// Sparse attention, lane-pair scheme: one wave per (b,h,i).
// Score phase: 2 lanes per neighbor (jj = lane>>1, half = lane&1); each lane
// holds half of q (32 floats) and computes a 32-elem partial dot; one
// shfl_xor(1) completes it. Softmax once per wave. V phase: lane = dim.
// ---------------------------------------------------------------------------
__global__ __launch_bounds__(256)
void attn_kernel(const float* __restrict__ qkv,
                 const int* __restrict__ topk_idx, const float* __restrict__ topk_dist,
                 const float* __restrict__ log_tau_p, const float* __restrict__ attn_scale_p,
                 unsigned short* __restrict__ out)
{
    int gw   = (blockIdx.x * blockDim.x + threadIdx.x) >> 6;
    int lane = threadIdx.x & 63;
    if (gw >= B_ * NH_ * N_) return;
    int b = gw / (NH_ * N_);
    int r = gw % (NH_ * N_);
    int h = r / N_;
    int i = r % N_;
    int tok = b * N_ + i;

    float tau    = fmaxf(__expf(*log_tau_p), 1e-8f);
    float ascale = *attn_scale_p;

    const int*   idxp = topk_idx  + (size_t)tok * K_;
    const float* dstp = topk_dist + (size_t)tok * K_;
    int   my_idx  = idxp[lane & 31];
    float my_dist = dstp[lane & 31];

    int jj   = lane >> 1;
    int half = lane & 1;

    // q half: 32 floats
    const float4* qp = (const float4*)(qkv + (size_t)tok * QKV_ + h * HD_ + half * 32);
    float4 qv[8];
#pragma unroll
    for (int u = 0; u < 8; u++) qv[u] = qp[u];

    // k partial dot for neighbor jj
    int nb = __shfl(my_idx, jj);
    const float4* kp = (const float4*)(qkv + (size_t)(b * N_ + nb) * QKV_ + DIM_ + h * HD_ + half * 32);
    float dot = 0.f;
#pragma unroll
    for (int u = 0; u < 8; u++) {
        float4 kv4 = kp[u];
        dot += qv[u].x * kv4.x + qv[u].y * kv4.y + qv[u].z * kv4.z + qv[u].w * kv4.w;
    }
    dot += __shfl_xor(dot, 1);   // full dot on both lanes of the pair

    float fs = dot * 0.125f;                        // 1/sqrt(64)
    float gs = -__shfl(my_dist, jj) / tau;
    float s  = ascale * tanh_fast(fs + gs);

    // softmax over the 32 scores (each duplicated on a lane pair)
    float mx = s;
#pragma unroll
    for (int off = 32; off; off >>= 1) mx = fmaxf(mx, __shfl_xor(mx, off));
    float e  = __expf(s - mx);
    float ec = half ? 0.f : e;
#pragma unroll
    for (int off = 32; off; off >>= 1) ec += __shfl_xor(ec, off);
    float inv = 1.f / ec;

    // V phase: lane = output dim
    const float* vb = qkv + 2 * DIM_ + h * HD_ + lane;
    float acc = 0.f;
#pragma unroll
    for (int t2 = 0; t2 < K_; t2++) {
        float w  = __shfl(e, t2 * 2) * inv;
        int   nj = __shfl(my_idx, t2);
        acc += w * vb[(size_t)(b * N_ + nj) * QKV_];
    }
    out[(size_t)tok * DIM_ + h * HD_ + lane] = f2bf(acc);
}

// ---------------------------------------------------------------------------
extern "C" void kernel_launch(void* const* d_in, const int* in_sizes, int n_in,
                              void* d_out, int out_size, void* d_ws, size_t ws_size,
                              hipStream_t stream)
{
    const float* x          = (const float*)d_in[0];
    const float* positions  = (const float*)d_in[1];
    const float* c_p        = (const float*)d_in[2];
    const float* Wq         = (const float*)d_in[3];
    const float* bq         = (const float*)d_in[4];
    const float* Wk         = (const float*)d_in[5];
    const float* bk         = (const float*)d_in[6];
    const float* Wv         = (const float*)d_in[7];
    const float* bv         = (const float*)d_in[8];
    const float* Wo         = (const float*)d_in[9];
    const float* bo         = (const float*)d_in[10];
    const float* W1         = (const float*)d_in[11];
    const float* b1         = (const float*)d_in[12];
    const float* W2         = (const float*)d_in[13];
    const float* b2         = (const float*)d_in[14];
    const float* ln1_scale  = (const float*)d_in[15];
    const float* ln1_bias   = (const float*)d_in[16];
    const float* ln2_scale  = (const float*)d_in[17];
    const float* ln2_bias   = (const float*)d_in[18];
    const float* log_tau    = (const float*)d_in[19];
    const float* attn_scale = (const float*)d_in[20];

    char* p = (char*)d_ws;
    unsigned short* qkvWt  = (unsigned short*)p; p += (size_t)QKV_ * DIM_ * 2;   // [1536][512] bf16
    unsigned short* WoT    = (unsigned short*)p; p += (size_t)DIM_ * DIM_ * 2;   // [512][512]
    unsigned short* W1T    = (unsigned short*)p; p += (size_t)FFN_ * DIM_ * 2;   // [2048][512]
    unsigned short* W2T    = (unsigned short*)p; p += (size_t)DIM_ * FFN_ * 2;   // [512][2048]
    float*          qkv_b  = (float*)p;          p += (size_t)QKV_ * 4;
    unsigned short* xn     = (unsigned short*)p; p += (size_t)TOK_ * DIM_ * 2;   // bf16
    float*          qkv    = (float*)p;          p += (size_t)TOK_ * QKV_ * 4;   // fp32
    unsigned short* attn_o = (unsigned short*)p; p += (size_t)TOK_ * DIM_ * 2;   // bf16
    float*          x1     = (float*)p;          p += (size_t)TOK_ * DIM_ * 4;
    unsigned short* x2n    = (unsigned short*)p; p += (size_t)TOK_ * DIM_ * 2;
    unsigned short* hbuf   = (unsigned short*)p; p += (size_t)TOK_ * FFN_ * 2;
    float*          pos_sq = (float*)p;          p += (size_t)TOK_ * 4;
    float*          tk_d   = (float*)p;          p += (size_t)TOK_ * K_ * 4;
    int*            tk_i   = (int*)p;            p += (size_t)TOK_ * K_ * 4;

    // --- weight prep (runs every call; weights are restored each launch) ---
    dim3 tc512(DIM_/32, DIM_/32);     // 16x16
    transpose_cast_kernel<<<tc512, 256, 0, stream>>>(Wq, qkvWt,                 DIM_, DIM_);
    transpose_cast_kernel<<<tc512, 256, 0, stream>>>(Wk, qkvWt + DIM_*DIM_,     DIM_, DIM_);
    transpose_cast_kernel<<<tc512, 256, 0, stream>>>(Wv, qkvWt + 2*DIM_*DIM_,   DIM_, DIM_);
    transpose_cast_kernel<<<tc512, 256, 0, stream>>>(Wo, WoT,                   DIM_, DIM_);
    transpose_cast_kernel<<<dim3(FFN_/32, DIM_/32), 256, 0, stream>>>(W1, W1T,  DIM_, FFN_);
    transpose_cast_kernel<<<dim3(DIM_/32, FFN_/32), 256, 0, stream>>>(W2, W2T,  FFN_, DIM_);
    pack_bias3_kernel<<<QKV_/256, 256, 0, stream>>>(bq, bk, bv, qkv_b);

    // --- LN1 -> bf16 ---
    layernorm_kernel<<<TOK_/4, 256, 0, stream>>>(x, ln1_scale, ln1_bias, xn);

    // --- fused QKV GEMM: [4096,512] @ [512,1536] -> fp32 qkv ---
    gemm_bf16_kernel<0><<<dim3(QKV_/128, TOK_/128), 256, 0, stream>>>(
        xn, qkvWt, qkv_b, nullptr, qkv, nullptr, TOK_, QKV_, DIM_);

    // --- distances + top-k ---
    pos_sq_kernel<<<TOK_/256, 256, 0, stream>>>(positions, pos_sq);
    dist_topk_wave_kernel<<<TOK_/4, 256, 0, stream>>>(positions, pos_sq, c_p, tk_i, tk_d);

    // --- sparse attention -> bf16 ---
    attn_kernel<<<(B_*NH_*N_)/4, 256, 0, stream>>>(qkv, tk_i, tk_d, log_tau, attn_scale, attn_o);

    // --- x1 = x + attn_o @ Wo + bo (fp32) ---
    gemm_bf16_kernel<1><<<dim3(DIM_/128, TOK_/128), 256, 0, stream>>>(
        attn_o, WoT, bo, x, x1, nullptr, TOK_, DIM_, DIM_);

    // --- LN2 -> bf16 ---
    layernorm_kernel<<<TOK_/4, 256, 0, stream>>>(x1, ln2_scale, ln2_bias, x2n);

    // --- FFN1: gelu(x2n @ W1 + b1) -> bf16 h ---
    gemm_bf16_kernel<2><<<dim3(FFN_/128, TOK_/128), 256, 0, stream>>>(
        x2n, W1T, b1, nullptr, nullptr, hbuf, TOK_, FFN_, DIM_);

    // --- FFN2: out = x1 + h @ W2 + b2 (fp32) ---
    gemm_bf16_kernel<1><<<dim3(DIM_/128, TOK_/128), 256, 0, stream>>>(
        hbuf, W2T, b2, x1, (float*)d_out, nullptr, TOK_, DIM_, FFN_);
}

// Round 4
// 353.658 us; speedup vs baseline: 2.4693x; 1.0841x over previous
//
#include <hip/hip_runtime.h>
#include <math.h>

#define B_   2
#define N_   2048
#define DIM_ 512
#define NH_  8
#define HD_  64
#define K_   32
#define PD_  16
#define TOK_ (B_*N_)     // 4096 rows
#define FFN_ 2048
#define QKV_ (3*DIM_)    // 1536

typedef __bf16 bf16x8 __attribute__((ext_vector_type(8)));
typedef float  f32x4  __attribute__((ext_vector_type(4)));

__device__ __forceinline__ unsigned short f2bf(float f) {
    unsigned int u = __float_as_uint(f);
    u = (u + 0x7fffu + ((u >> 16) & 1u)) >> 16;
    return (unsigned short)u;
}

__device__ __forceinline__ float gelu_tanh(float x) {
    float x3 = x * x * x;
    return 0.5f * x * (1.f + tanhf(0.7978845608028654f * (x + 0.044715f * x3)));
}

__device__ __forceinline__ float tanh_fast(float x) {
    // tanh(x) = 1 - 2/(exp(2x)+1); exact at both saturation ends
    float e = __expf(2.f * x);
    return 1.f - 2.f / (e + 1.f);
}

__device__ __forceinline__ int lane_mbcnt(unsigned long long m) {
    return __builtin_amdgcn_mbcnt_hi((unsigned)(m >> 32),
           __builtin_amdgcn_mbcnt_lo((unsigned)m, 0));
}

// async global->LDS, 16B per lane. LDS dst must be wave-uniform base + lane*16.
#define GLOAD_LDS16(g, l) __builtin_amdgcn_global_load_lds(                        \
    (const __attribute__((address_space(1))) unsigned int*)(const void*)(g),       \
    (__attribute__((address_space(3))) unsigned int*)(void*)(l), 16, 0, 0)

// ---------------------------------------------------------------------------
// LayerNorm: one wave per row of 512; writes bf16.
// ---------------------------------------------------------------------------
__global__ void layernorm_kernel(const float* __restrict__ x,
                                 const float* __restrict__ scale,
                                 const float* __restrict__ bias,
                                 unsigned short* __restrict__ y)
{
    int wave = (blockIdx.x * blockDim.x + threadIdx.x) >> 6;
    int lane = threadIdx.x & 63;
    if (wave >= TOK_) return;
    const float* xr = x + (size_t)wave * DIM_;
    float v[8];
    float s = 0.f;
#pragma unroll
    for (int i = 0; i < 8; i++) { v[i] = xr[lane + i*64]; s += v[i]; }
#pragma unroll
    for (int off = 32; off; off >>= 1) s += __shfl_xor(s, off);
    float mean = s * (1.f / DIM_);
    float vs = 0.f;
#pragma unroll
    for (int i = 0; i < 8; i++) { float d = v[i] - mean; vs += d*d; }
#pragma unroll
    for (int off = 32; off; off >>= 1) vs += __shfl_xor(vs, off);
    float inv = rsqrtf(vs * (1.f / DIM_) + 1e-6f);
    unsigned short* yr = y + (size_t)wave * DIM_;
#pragma unroll
    for (int i = 0; i < 8; i++) {
        int c = lane + i*64;
        yr[c] = f2bf((v[i] - mean) * inv * scale[c] + bias[c]);
    }
}

// ---------------------------------------------------------------------------
// Transpose + cast: Wt[n][k] = bf16(W[k][n]).  32x32 LDS tile, 256 threads.
// ---------------------------------------------------------------------------
__global__ void transpose_cast_kernel(const float* __restrict__ W,
                                      unsigned short* __restrict__ Wt,
                                      int Kd, int Nw)
{
    __shared__ float tile[32][33];
    int n0 = blockIdx.x * 32, k0 = blockIdx.y * 32;
    int tx = threadIdx.x & 31, ty = threadIdx.x >> 5;   // ty in 0..7
#pragma unroll
    for (int i = 0; i < 32; i += 8)
        tile[ty + i][tx] = W[(size_t)(k0 + ty + i) * Nw + n0 + tx];
    __syncthreads();
#pragma unroll
    for (int i = 0; i < 32; i += 8)
        Wt[(size_t)(n0 + ty + i) * Kd + k0 + tx] = f2bf(tile[tx][ty + i]);
}

__global__ void pack_bias3_kernel(const float* __restrict__ a, const float* __restrict__ b,
                                  const float* __restrict__ c, float* __restrict__ o)
{
    int i = blockIdx.x * 256 + threadIdx.x;
    if (i < DIM_)            o[i] = a[i];
    else if (i < 2*DIM_)     o[i] = b[i - DIM_];
    else if (i < 3*DIM_)     o[i] = c[i - 2*DIM_];
}

// ---------------------------------------------------------------------------
// bf16 MFMA GEMM: C[M,N] = A[M,Kd] @ Bt[N,Kd]^T (+bias / +res / gelu)
// 128x128 tile, BK=32, 256 threads (4 waves 2x2), 16x16x32 bf16 MFMA.
// EPI: 0 = +bias -> fp32 ; 1 = +bias+res -> fp32 ; 2 = gelu(+bias) -> bf16
// ---------------------------------------------------------------------------
template<int EPI>
__global__ __launch_bounds__(256)
void gemm_bf16_kernel(const unsigned short* __restrict__ A,
                      const unsigned short* __restrict__ Bt,
                      const float* __restrict__ bias,
                      const float* __restrict__ res,
                      float* __restrict__ Cf,
                      unsigned short* __restrict__ Cb,
                      int M, int N, int Kd)
{
    __shared__ unsigned short As[128*32];   // 8 KB
    __shared__ unsigned short Bs[128*32];   // 8 KB

    int t    = threadIdx.x;
    int lane = t & 63;
    int wid  = t >> 6;
    int wm   = wid >> 1, wn = wid & 1;

    int bm0 = blockIdx.y * 128;
    int bn0 = blockIdx.x * 128;

    int srow = t >> 2;          // 0..63
    int scol = (t & 3) * 8;     // 0,8,16,24

    const unsigned short* gA0 = A  + (size_t)(bm0 + srow)      * Kd + scol;
    const unsigned short* gA1 = A  + (size_t)(bm0 + 64 + srow) * Kd + scol;
    const unsigned short* gB0 = Bt + (size_t)(bn0 + srow)      * Kd + scol;
    const unsigned short* gB1 = Bt + (size_t)(bn0 + 64 + srow) * Kd + scol;

    unsigned short* lA0 = As + t*8;          // == (srow*32 + scol)
    unsigned short* lA1 = As + 2048 + t*8;
    unsigned short* lB0 = Bs + t*8;
    unsigned short* lB1 = Bs + 2048 + t*8;

    f32x4 acc[4][4] = {};

    int arow = wm*64 + (lane & 15);       // + mi*16
    int brow = wn*64 + (lane & 15);       // + ni*16
    int kfrag = (lane >> 4) * 8;

    for (int k0 = 0; k0 < Kd; k0 += 32) {
        GLOAD_LDS16(gA0 + k0, lA0);
        GLOAD_LDS16(gA1 + k0, lA1);
        GLOAD_LDS16(gB0 + k0, lB0);
        GLOAD_LDS16(gB1 + k0, lB1);
        __syncthreads();

        bf16x8 af[4], bf[4];
#pragma unroll
        for (int mi = 0; mi < 4; mi++)
            af[mi] = *(const bf16x8*)(As + (arow + mi*16)*32 + kfrag);
#pragma unroll
        for (int ni = 0; ni < 4; ni++)
            bf[ni] = *(const bf16x8*)(Bs + (brow + ni*16)*32 + kfrag);
#pragma unroll
        for (int mi = 0; mi < 4; mi++)
#pragma unroll
            for (int ni = 0; ni < 4; ni++)
                acc[mi][ni] = __builtin_amdgcn_mfma_f32_16x16x32_bf16(
                    af[mi], bf[ni], acc[mi][ni], 0, 0, 0);
        __syncthreads();
    }

    // epilogue: D row = (lane>>4)*4 + r, col = lane&15 within each 16x16 tile
#pragma unroll
    for (int mi = 0; mi < 4; mi++) {
#pragma unroll
        for (int ni = 0; ni < 4; ni++) {
            int col = bn0 + wn*64 + ni*16 + (lane & 15);
            float bv = bias[col];
#pragma unroll
            for (int r = 0; r < 4; r++) {
                int row = bm0 + wm*64 + mi*16 + (lane >> 4)*4 + r;
                float val = acc[mi][ni][r] + bv;
                if (EPI == 1) val += res[(size_t)row * N + col];
                if (EPI == 2) {
                    val = gelu_tanh(val);
                    Cb[(size_t)row * N + col] = f2bf(val);
                } else {
                    Cf[(size_t)row * N + col] = val;
                }
            }
        }
    }
}

// ---------------------------------------------------------------------------
// positions squared norms
// ---------------------------------------------------------------------------
__global__ void pos_sq_kernel(const float* __restrict__ pos, float* __restrict__ pos_sq)
{
    int i = blockIdx.x * blockDim.x + threadIdx.x;
    if (i >= TOK_) return;
    const float4* p = (const float4*)(pos + (size_t)i * PD_);
    float s = 0.f;
#pragma unroll
    for (int d = 0; d < 4; d++) {
        float4 q = p[d];
        s += q.x*q.x + q.y*q.y + q.z*q.z + q.w*q.w;
    }
    pos_sq[i] = s;
}

// ---------------------------------------------------------------------------
// Poincare dist + exact top-K via radix-select. One wave per row; 2048 rank
// values (pre-acosh "arg", monotone in dist) in regs, 32/lane as raw bits.
// Bitwise binary search for the 32nd-smallest pattern T (counts via ballot +
// scalar popcount, co-issued on the SALU pipe), then one extraction pass
// (ballot + mbcnt prefix). Ties at T resolved by ascending j (= ascending tt,
// then ascending lane) == jax.lax.top_k lower-index-first semantics. acosh
// applied only to the 32 winners.
// ---------------------------------------------------------------------------
__global__ __launch_bounds__(256)
void dist_topk_radix_kernel(const float* __restrict__ pos, const float* __restrict__ pos_sq,
                            const float* __restrict__ c_ptr,
                            int* __restrict__ topk_idx, float* __restrict__ topk_dist)
{
    __shared__ int      sj[4][K_];
    __shared__ unsigned sr[4][K_];

    int wid  = threadIdx.x >> 6;
    int lane = threadIdx.x & 63;
    int bi   = blockIdx.x * 4 + wid;      // 0..TOK_-1
    int b    = bi >> 11;                  // / N_
    float c  = *c_ptr;
    float inv_sqrt_c = rsqrtf(c);

    const float4* pi4 = (const float4*)(pos + (size_t)bi * PD_);
    float4 p0 = pi4[0], p1 = pi4[1], p2 = pi4[2], p3 = pi4[3];
    float ni = pos_sq[bi];
    float omci = 1.f - c * ni;

    const float* pb  = pos + (size_t)b * N_ * PD_;
    const float* sqb = pos_sq + b * N_;

    unsigned rb[32];
#pragma unroll
    for (int tt = 0; tt < 32; tt++) {
        int j = tt*64 + lane;
        const float4* pj = (const float4*)(pb + (size_t)j * PD_);
        float4 q0 = pj[0], q1 = pj[1], q2 = pj[2], q3 = pj[3];
        float diff =
            (p0.x-q0.x)*(p0.x-q0.x) + (p0.y-q0.y)*(p0.y-q0.y) +
            (p0.z-q0.z)*(p0.z-q0.z) + (p0.w-q0.w)*(p0.w-q0.w) +
            (p1.x-q1.x)*(p1.x-q1.x) + (p1.y-q1.y)*(p1.y-q1.y) +
            (p1.z-q1.z)*(p1.z-q1.z) + (p1.w-q1.w)*(p1.w-q1.w) +
            (p2.x-q2.x)*(p2.x-q2.x) + (p2.y-q2.y)*(p2.y-q2.y) +
            (p2.z-q2.z)*(p2.z-q2.z) + (p2.w-q2.w)*(p2.w-q2.w) +
            (p3.x-q3.x)*(p3.x-q3.x) + (p3.y-q3.y)*(p3.y-q3.y) +
            (p3.z-q3.z)*(p3.z-q3.z) + (p3.w-q3.w)*(p3.w-q3.w);
        float den = fmaxf(omci * (1.f - c * sqb[j]), 1e-8f);
        float arg = fmaxf(1.f + 2.f * c * diff / den, 1.f + 1e-7f);
        rb[tt] = __float_as_uint(arg);   // arg >= 1.0 > 0: bits monotone in dist
    }

    // --- radix select: T = K-th smallest bit pattern over all 2048 ---
    unsigned T = 0;
    for (int bit = 30; bit >= 0; --bit) {
        unsigned probe = T | (1u << bit);
        int cnt = 0;
#pragma unroll
        for (int tt = 0; tt < 32; tt++)
            cnt += __popcll(__ballot(rb[tt] < probe));
        if (cnt < K_) T = probe;
    }

    int cnt_lt = 0;
#pragma unroll
    for (int tt = 0; tt < 32; tt++)
        cnt_lt += __popcll(__ballot(rb[tt] < T));
    int m = K_ - cnt_lt;                  // how many equals (lowest j) to take

    // --- extraction: lt elements first, then first m equals in j-order ---
    int ltbase = 0, eqbase = 0;
#pragma unroll
    for (int tt = 0; tt < 32; tt++) {
        bool is_lt = rb[tt] < T;
        bool is_eq = rb[tt] == T;
        unsigned long long mlt = __ballot(is_lt);
        unsigned long long meq = __ballot(is_eq);
        int pos_lt = ltbase + lane_mbcnt(mlt);
        int pos_eq = eqbase + lane_mbcnt(meq);
        if (is_lt) {
            sj[wid][pos_lt] = tt*64 + lane;
            sr[wid][pos_lt] = rb[tt];
        } else if (is_eq && pos_eq < m) {
            sj[wid][cnt_lt + pos_eq] = tt*64 + lane;
            sr[wid][cnt_lt + pos_eq] = rb[tt];
        }
        ltbase += __popcll(mlt);
        eqbase += __popcll(meq);
    }
    __syncthreads();

    if (lane < K_) {
        float arg = __uint_as_float(sr[wid][lane]);
        topk_idx [(size_t)bi * K_ + lane] = sj[wid][lane];
        topk_dist[(size_t)bi * K_ + lane] = acoshf(arg) * inv_sqrt_c;
    }
}

// ---------------------------------------------------------------------------
// Sparse attention, lane-pair scheme: one wave per (b,h,i).
// ---------------------------------------------------------------------------
__global__ __launch_bounds__(256)
void attn_kernel(const float* __restrict__ qkv,
                 const int* __restrict__ topk_idx, const float* __restrict__ topk_dist,
                 const float* __restrict__ log_tau_p, const float* __restrict__ attn_scale_p,
                 unsigned short* __restrict__ out)
{
    int gw   = (blockIdx.x * blockDim.x + threadIdx.x) >> 6;
    int lane = threadIdx.x & 63;
    if (gw >= B_ * NH_ * N_) return;
    int b = gw / (NH_ * N_);
    int r = gw % (NH_ * N_);
    int h = r / N_;
    int i = r % N_;
    int tok = b * N_ + i;

    float tau    = fmaxf(__expf(*log_tau_p), 1e-8f);
    float ascale = *attn_scale_p;

    const int*   idxp = topk_idx  + (size_t)tok * K_;
    const float* dstp = topk_dist + (size_t)tok * K_;
    int   my_idx  = idxp[lane & 31];
    float my_dist = dstp[lane & 31];

    int jj   = lane >> 1;
    int half = lane & 1;

    // q half: 32 floats
    const float4* qp = (const float4*)(qkv + (size_t)tok * QKV_ + h * HD_ + half * 32);
    float4 qv[8];
#pragma unroll
    for (int u = 0; u < 8; u++) qv[u] = qp[u];

    // k partial dot for neighbor jj
    int nb = __shfl(my_idx, jj);
    const float4* kp = (const float4*)(qkv + (size_t)(b * N_ + nb) * QKV_ + DIM_ + h * HD_ + half * 32);
    float dot = 0.f;
#pragma unroll
    for (int u = 0; u < 8; u++) {
        float4 kv4 = kp[u];
        dot += qv[u].x * kv4.x + qv[u].y * kv4.y + qv[u].z * kv4.z + qv[u].w * kv4.w;
    }
    dot += __shfl_xor(dot, 1);   // full dot on both lanes of the pair

    float fs = dot * 0.125f;                        // 1/sqrt(64)
    float gs = -__shfl(my_dist, jj) / tau;
    float s  = ascale * tanh_fast(fs + gs);

    // softmax over the 32 scores (each duplicated on a lane pair)
    float mx = s;
#pragma unroll
    for (int off = 32; off; off >>= 1) mx = fmaxf(mx, __shfl_xor(mx, off));
    float e  = __expf(s - mx);
    float ec = half ? 0.f : e;
#pragma unroll
    for (int off = 32; off; off >>= 1) ec += __shfl_xor(ec, off);
    float inv = 1.f / ec;

    // V phase: lane = output dim
    const float* vb = qkv + 2 * DIM_ + h * HD_ + lane;
    float acc = 0.f;
#pragma unroll
    for (int t2 = 0; t2 < K_; t2++) {
        float w  = __shfl(e, t2 * 2) * inv;
        int   nj = __shfl(my_idx, t2);
        acc += w * vb[(size_t)(b * N_ + nj) * QKV_];
    }
    out[(size_t)tok * DIM_ + h * HD_ + lane] = f2bf(acc);
}

// ---------------------------------------------------------------------------
extern "C" void kernel_launch(void* const* d_in, const int* in_sizes, int n_in,
                              void* d_out, int out_size, void* d_ws, size_t ws_size,
                              hipStream_t stream)
{
    const float* x          = (const float*)d_in[0];
    const float* positions  = (const float*)d_in[1];
    const float* c_p        = (const float*)d_in[2];
    const float* Wq         = (const float*)d_in[3];
    const float* bq         = (const float*)d_in[4];
    const float* Wk         = (const float*)d_in[5];
    const float* bk         = (const float*)d_in[6];
    const float* Wv         = (const float*)d_in[7];
    const float* bv         = (const float*)d_in[8];
    const float* Wo         = (const float*)d_in[9];
    const float* bo         = (const float*)d_in[10];
    const float* W1         = (const float*)d_in[11];
    const float* b1         = (const float*)d_in[12];
    const float* W2         = (const float*)d_in[13];
    const float* b2         = (const float*)d_in[14];
    const float* ln1_scale  = (const float*)d_in[15];
    const float* ln1_bias   = (const float*)d_in[16];
    const float* ln2_scale  = (const float*)d_in[17];
    const float* ln2_bias   = (const float*)d_in[18];
    const float* log_tau    = (const float*)d_in[19];
    const float* attn_scale = (const float*)d_in[20];

    char* p = (char*)d_ws;
    unsigned short* qkvWt  = (unsigned short*)p; p += (size_t)QKV_ * DIM_ * 2;   // [1536][512] bf16
    unsigned short* WoT    = (unsigned short*)p; p += (size_t)DIM_ * DIM_ * 2;   // [512][512]
    unsigned short* W1T    = (unsigned short*)p; p += (size_t)FFN_ * DIM_ * 2;   // [2048][512]
    unsigned short* W2T    = (unsigned short*)p; p += (size_t)DIM_ * FFN_ * 2;   // [512][2048]
    float*          qkv_b  = (float*)p;          p += (size_t)QKV_ * 4;
    unsigned short* xn     = (unsigned short*)p; p += (size_t)TOK_ * DIM_ * 2;   // bf16
    float*          qkv    = (float*)p;          p += (size_t)TOK_ * QKV_ * 4;   // fp32
    unsigned short* attn_o = (unsigned short*)p; p += (size_t)TOK_ * DIM_ * 2;   // bf16
    float*          x1     = (float*)p;          p += (size_t)TOK_ * DIM_ * 4;
    unsigned short* x2n    = (unsigned short*)p; p += (size_t)TOK_ * DIM_ * 2;
    unsigned short* hbuf   = (unsigned short*)p; p += (size_t)TOK_ * FFN_ * 2;
    float*          pos_sq = (float*)p;          p += (size_t)TOK_ * 4;
    float*          tk_d   = (float*)p;          p += (size_t)TOK_ * K_ * 4;
    int*            tk_i   = (int*)p;            p += (size_t)TOK_ * K_ * 4;

    // --- weight prep (runs every call; weights are restored each launch) ---
    dim3 tc512(DIM_/32, DIM_/32);     // 16x16
    transpose_cast_kernel<<<tc512, 256, 0, stream>>>(Wq, qkvWt,                 DIM_, DIM_);
    transpose_cast_kernel<<<tc512, 256, 0, stream>>>(Wk, qkvWt + DIM_*DIM_,     DIM_, DIM_);
    transpose_cast_kernel<<<tc512, 256, 0, stream>>>(Wv, qkvWt + 2*DIM_*DIM_,   DIM_, DIM_);
    transpose_cast_kernel<<<tc512, 256, 0, stream>>>(Wo, WoT,                   DIM_, DIM_);
    transpose_cast_kernel<<<dim3(FFN_/32, DIM_/32), 256, 0, stream>>>(W1, W1T,  DIM_, FFN_);
    transpose_cast_kernel<<<dim3(DIM_/32, FFN_/32), 256, 0, stream>>>(W2, W2T,  FFN_, DIM_);
    pack_bias3_kernel<<<QKV_/256, 256, 0, stream>>>(bq, bk, bv, qkv_b);

    // --- LN1 -> bf16 ---
    layernorm_kernel<<<TOK_/4, 256, 0, stream>>>(x, ln1_scale, ln1_bias, xn);

    // --- fused QKV GEMM: [4096,512] @ [512,1536] -> fp32 qkv ---
    gemm_bf16_kernel<0><<<dim3(QKV_/128, TOK_/128), 256, 0, stream>>>(
        xn, qkvWt, qkv_b, nullptr, qkv, nullptr, TOK_, QKV_, DIM_);

    // --- distances + top-k ---
    pos_sq_kernel<<<TOK_/256, 256, 0, stream>>>(positions, pos_sq);
    dist_topk_radix_kernel<<<TOK_/4, 256, 0, stream>>>(positions, pos_sq, c_p, tk_i, tk_d);

    // --- sparse attention -> bf16 ---
    attn_kernel<<<(B_*NH_*N_)/4, 256, 0, stream>>>(qkv, tk_i, tk_d, log_tau, attn_scale, attn_o);

    // --- x1 = x + attn_o @ Wo + bo (fp32) ---
    gemm_bf16_kernel<1><<<dim3(DIM_/128, TOK_/128), 256, 0, stream>>>(
        attn_o, WoT, bo, x, x1, nullptr, TOK_, DIM_, DIM_);

    // --- LN2 -> bf16 ---
    layernorm_kernel<<<TOK_/4, 256, 0, stream>>>(x1, ln2_scale, ln2_bias, x2n);

    // --- FFN1: gelu(x2n @ W1 + b1) -> bf16 h ---
    gemm_bf16_kernel<2><<<dim3(FFN_/128, TOK_/128), 256, 0, stream>>>(
        x2n, W1T, b1, nullptr, nullptr, hbuf, TOK_, FFN_, DIM_);

    // --- FFN2: out = x1 + h @ W2 + b2 (fp32) ---
    gemm_bf16_kernel<1><<<dim3(DIM_/128, TOK_/128), 256, 0, stream>>>(
        hbuf, W2T, b2, x1, (float*)d_out, nullptr, TOK_, DIM_, FFN_);
}

// Round 5
// 310.492 us; speedup vs baseline: 2.8126x; 1.1390x over previous
//
#include <hip/hip_runtime.h>
#include <math.h>

#define B_   2
#define N_   2048
#define DIM_ 512
#define NH_  8
#define HD_  64
#define K_   32
#define PD_  16
#define TOK_ (B_*N_)     // 4096 rows
#define FFN_ 2048
#define QKV_ (3*DIM_)    // 1536
#define KV_  1024        // k|v bf16 row length

typedef __bf16 bf16x8 __attribute__((ext_vector_type(8)));
typedef float  f32x4  __attribute__((ext_vector_type(4)));

__device__ __forceinline__ unsigned short f2bf(float f) {
    unsigned int u = __float_as_uint(f);
    u = (u + 0x7fffu + ((u >> 16) & 1u)) >> 16;
    return (unsigned short)u;
}

__device__ __forceinline__ float bflo(unsigned u) { return __uint_as_float(u << 16); }
__device__ __forceinline__ float bfhi(unsigned u) { return __uint_as_float(u & 0xffff0000u); }

__device__ __forceinline__ float gelu_tanh(float x) {
    float x3 = x * x * x;
    return 0.5f * x * (1.f + tanhf(0.7978845608028654f * (x + 0.044715f * x3)));
}

__device__ __forceinline__ float tanh_fast(float x) {
    float e = __expf(2.f * x);
    return 1.f - 2.f / (e + 1.f);
}

__device__ __forceinline__ int lane_mbcnt(unsigned long long m) {
    return __builtin_amdgcn_mbcnt_hi((unsigned)(m >> 32),
           __builtin_amdgcn_mbcnt_lo((unsigned)m, 0));
}

// async global->LDS, 16B per lane. LDS dst must be wave-uniform base + lane*16.
#define GLOAD_LDS16(g, l) __builtin_amdgcn_global_load_lds(                        \
    (const __attribute__((address_space(1))) unsigned int*)(const void*)(g),       \
    (__attribute__((address_space(3))) unsigned int*)(void*)(l), 16, 0, 0)

// ---------------------------------------------------------------------------
// LayerNorm: one wave per row of 512; writes bf16.
// ---------------------------------------------------------------------------
__global__ void layernorm_kernel(const float* __restrict__ x,
                                 const float* __restrict__ scale,
                                 const float* __restrict__ bias,
                                 unsigned short* __restrict__ y)
{
    int wave = (blockIdx.x * blockDim.x + threadIdx.x) >> 6;
    int lane = threadIdx.x & 63;
    if (wave >= TOK_) return;
    const float* xr = x + (size_t)wave * DIM_;
    float v[8];
    float s = 0.f;
#pragma unroll
    for (int i = 0; i < 8; i++) { v[i] = xr[lane + i*64]; s += v[i]; }
#pragma unroll
    for (int off = 32; off; off >>= 1) s += __shfl_xor(s, off);
    float mean = s * (1.f / DIM_);
    float vs = 0.f;
#pragma unroll
    for (int i = 0; i < 8; i++) { float d = v[i] - mean; vs += d*d; }
#pragma unroll
    for (int off = 32; off; off >>= 1) vs += __shfl_xor(vs, off);
    float inv = rsqrtf(vs * (1.f / DIM_) + 1e-6f);
    unsigned short* yr = y + (size_t)wave * DIM_;
#pragma unroll
    for (int i = 0; i < 8; i++) {
        int c = lane + i*64;
        yr[c] = f2bf((v[i] - mean) * inv * scale[c] + bias[c]);
    }
}

// ---------------------------------------------------------------------------
// ONE prep kernel: 6 weight transposes (32x32 tiles) + bias3 pack + pos_sq.
// block id ranges: [0,256) Wq, [256,512) Wk, [512,768) Wv, [768,1024) Wo,
// [1024,2048) W1, [2048,3072) W2, [3072,3079) bias pack, [3079,3095) pos_sq.
// ---------------------------------------------------------------------------
__global__ void prep_kernel(const float* __restrict__ Wq, const float* __restrict__ Wk,
                            const float* __restrict__ Wv, const float* __restrict__ Wo,
                            const float* __restrict__ W1, const float* __restrict__ W2,
                            const float* __restrict__ bq, const float* __restrict__ bk,
                            const float* __restrict__ bv,
                            unsigned short* __restrict__ qkvWt,
                            unsigned short* __restrict__ WoT,
                            unsigned short* __restrict__ W1T,
                            unsigned short* __restrict__ W2T,
                            float* __restrict__ qkv_b,
                            const float* __restrict__ pos,
                            float* __restrict__ pos_sq)
{
    int id = blockIdx.x;
    if (id >= 3079) {                 // pos_sq
        int i = (id - 3079) * 256 + threadIdx.x;
        if (i < TOK_) {
            const float4* p = (const float4*)(pos + (size_t)i * PD_);
            float s = 0.f;
#pragma unroll
            for (int d = 0; d < 4; d++) {
                float4 q = p[d];
                s += q.x*q.x + q.y*q.y + q.z*q.z + q.w*q.w;
            }
            pos_sq[i] = s;
        }
        return;
    }
    if (id >= 3072) {                 // bias pack
        int i = (id - 3072) * 256 + threadIdx.x;
        if (i < DIM_)            qkv_b[i] = bq[i];
        else if (i < 2*DIM_)     qkv_b[i] = bk[i - DIM_];
        else if (i < 3*DIM_)     qkv_b[i] = bv[i - 2*DIM_];
        return;
    }

    const float* W; unsigned short* Wt; int Kd, Nw, nx, t;
    if      (id < 256)  { W = Wq; Wt = qkvWt;               Kd = 512;  Nw = 512;  nx = 16; t = id; }
    else if (id < 512)  { W = Wk; Wt = qkvWt + 512*512;     Kd = 512;  Nw = 512;  nx = 16; t = id - 256; }
    else if (id < 768)  { W = Wv; Wt = qkvWt + 2*512*512;   Kd = 512;  Nw = 512;  nx = 16; t = id - 512; }
    else if (id < 1024) { W = Wo; Wt = WoT;                 Kd = 512;  Nw = 512;  nx = 16; t = id - 768; }
    else if (id < 2048) { W = W1; Wt = W1T;                 Kd = 512;  Nw = 2048; nx = 64; t = id - 1024; }
    else                { W = W2; Wt = W2T;                 Kd = 2048; Nw = 512;  nx = 16; t = id - 2048; }

    __shared__ float tile[32][33];
    int n0 = (t % nx) * 32, k0 = (t / nx) * 32;
    int tx = threadIdx.x & 31, ty = threadIdx.x >> 5;
#pragma unroll
    for (int i = 0; i < 32; i += 8)
        tile[ty + i][tx] = W[(size_t)(k0 + ty + i) * Nw + n0 + tx];
    __syncthreads();
#pragma unroll
    for (int i = 0; i < 32; i += 8)
        Wt[(size_t)(n0 + ty + i) * Kd + k0 + tx] = f2bf(tile[tx][ty + i]);
}

// ---------------------------------------------------------------------------
// bf16 MFMA GEMM: C[M,N] = A[M,Kd] @ Bt[N,Kd]^T (+bias / +res / gelu)
// 128x128 tile, BK=32, 256 threads (4 waves 2x2), 16x16x32 bf16 MFMA.
// EPI: 0 = +bias -> fp32 ; 1 = +bias+res -> fp32 ; 2 = gelu(+bias) -> bf16
//      3 = QKV split: col<512 -> q fp32 [row][512]; col>=512 -> kv bf16 [row][1024]
// ---------------------------------------------------------------------------
template<int EPI>
__global__ __launch_bounds__(256)
void gemm_bf16_kernel(const unsigned short* __restrict__ A,
                      const unsigned short* __restrict__ Bt,
                      const float* __restrict__ bias,
                      const float* __restrict__ res,
                      float* __restrict__ Cf,
                      unsigned short* __restrict__ Cb,
                      int M, int N, int Kd)
{
    __shared__ unsigned short As[128*32];   // 8 KB
    __shared__ unsigned short Bs[128*32];   // 8 KB

    int t    = threadIdx.x;
    int lane = t & 63;
    int wid  = t >> 6;
    int wm   = wid >> 1, wn = wid & 1;

    int bm0 = blockIdx.y * 128;
    int bn0 = blockIdx.x * 128;

    int srow = t >> 2;          // 0..63
    int scol = (t & 3) * 8;     // 0,8,16,24

    const unsigned short* gA0 = A  + (size_t)(bm0 + srow)      * Kd + scol;
    const unsigned short* gA1 = A  + (size_t)(bm0 + 64 + srow) * Kd + scol;
    const unsigned short* gB0 = Bt + (size_t)(bn0 + srow)      * Kd + scol;
    const unsigned short* gB1 = Bt + (size_t)(bn0 + 64 + srow) * Kd + scol;

    unsigned short* lA0 = As + t*8;          // == (srow*32 + scol)
    unsigned short* lA1 = As + 2048 + t*8;
    unsigned short* lB0 = Bs + t*8;
    unsigned short* lB1 = Bs + 2048 + t*8;

    f32x4 acc[4][4] = {};

    int arow = wm*64 + (lane & 15);       // + mi*16
    int brow = wn*64 + (lane & 15);       // + ni*16
    int kfrag = (lane >> 4) * 8;

    for (int k0 = 0; k0 < Kd; k0 += 32) {
        GLOAD_LDS16(gA0 + k0, lA0);
        GLOAD_LDS16(gA1 + k0, lA1);
        GLOAD_LDS16(gB0 + k0, lB0);
        GLOAD_LDS16(gB1 + k0, lB1);
        __syncthreads();

        bf16x8 af[4], bf[4];
#pragma unroll
        for (int mi = 0; mi < 4; mi++)
            af[mi] = *(const bf16x8*)(As + (arow + mi*16)*32 + kfrag);
#pragma unroll
        for (int ni = 0; ni < 4; ni++)
            bf[ni] = *(const bf16x8*)(Bs + (brow + ni*16)*32 + kfrag);
#pragma unroll
        for (int mi = 0; mi < 4; mi++)
#pragma unroll
            for (int ni = 0; ni < 4; ni++)
                acc[mi][ni] = __builtin_amdgcn_mfma_f32_16x16x32_bf16(
                    af[mi], bf[ni], acc[mi][ni], 0, 0, 0);
        __syncthreads();
    }

    // epilogue: D row = (lane>>4)*4 + r, col = lane&15 within each 16x16 tile
#pragma unroll
    for (int mi = 0; mi < 4; mi++) {
#pragma unroll
        for (int ni = 0; ni < 4; ni++) {
            int col = bn0 + wn*64 + ni*16 + (lane & 15);
            float bv = bias[col];
#pragma unroll
            for (int r = 0; r < 4; r++) {
                int row = bm0 + wm*64 + mi*16 + (lane >> 4)*4 + r;
                float val = acc[mi][ni][r] + bv;
                if (EPI == 1) val += res[(size_t)row * N + col];
                if (EPI == 2) {
                    val = gelu_tanh(val);
                    Cb[(size_t)row * N + col] = f2bf(val);
                } else if (EPI == 3) {
                    if (col < DIM_) Cf[(size_t)row * DIM_ + col] = val;
                    else            Cb[(size_t)row * KV_ + (col - DIM_)] = f2bf(val);
                } else {
                    Cf[(size_t)row * N + col] = val;
                }
            }
        }
    }
}

// ---------------------------------------------------------------------------
// Poincare dist + exact top-K via radix-select (unchanged from R3).
// ---------------------------------------------------------------------------
__global__ __launch_bounds__(256)
void dist_topk_radix_kernel(const float* __restrict__ pos, const float* __restrict__ pos_sq,
                            const float* __restrict__ c_ptr,
                            int* __restrict__ topk_idx, float* __restrict__ topk_dist)
{
    __shared__ int      sj[4][K_];
    __shared__ unsigned sr[4][K_];

    int wid  = threadIdx.x >> 6;
    int lane = threadIdx.x & 63;
    int bi   = blockIdx.x * 4 + wid;      // 0..TOK_-1
    int b    = bi >> 11;                  // / N_
    float c  = *c_ptr;
    float inv_sqrt_c = rsqrtf(c);

    const float4* pi4 = (const float4*)(pos + (size_t)bi * PD_);
    float4 p0 = pi4[0], p1 = pi4[1], p2 = pi4[2], p3 = pi4[3];
    float ni = pos_sq[bi];
    float omci = 1.f - c * ni;

    const float* pb  = pos + (size_t)b * N_ * PD_;
    const float* sqb = pos_sq + b * N_;

    unsigned rb[32];
#pragma unroll
    for (int tt = 0; tt < 32; tt++) {
        int j = tt*64 + lane;
        const float4* pj = (const float4*)(pb + (size_t)j * PD_);
        float4 q0 = pj[0], q1 = pj[1], q2 = pj[2], q3 = pj[3];
        float diff =
            (p0.x-q0.x)*(p0.x-q0.x) + (p0.y-q0.y)*(p0.y-q0.y) +
            (p0.z-q0.z)*(p0.z-q0.z) + (p0.w-q0.w)*(p0.w-q0.w) +
            (p1.x-q1.x)*(p1.x-q1.x) + (p1.y-q1.y)*(p1.y-q1.y) +
            (p1.z-q1.z)*(p1.z-q1.z) + (p1.w-q1.w)*(p1.w-q1.w) +
            (p2.x-q2.x)*(p2.x-q2.x) + (p2.y-q2.y)*(p2.y-q2.y) +
            (p2.z-q2.z)*(p2.z-q2.z) + (p2.w-q2.w)*(p2.w-q2.w) +
            (p3.x-q3.x)*(p3.x-q3.x) + (p3.y-q3.y)*(p3.y-q3.y) +
            (p3.z-q3.z)*(p3.z-q3.z) + (p3.w-q3.w)*(p3.w-q3.w);
        float den = fmaxf(omci * (1.f - c * sqb[j]), 1e-8f);
        float arg = fmaxf(1.f + 2.f * c * diff / den, 1.f + 1e-7f);
        rb[tt] = __float_as_uint(arg);   // arg >= 1.0 > 0: bits monotone in dist
    }

    // --- radix select: T = K-th smallest bit pattern over all 2048 ---
    unsigned T = 0;
    for (int bit = 30; bit >= 0; --bit) {
        unsigned probe = T | (1u << bit);
        int cnt = 0;
#pragma unroll
        for (int tt = 0; tt < 32; tt++)
            cnt += __popcll(__ballot(rb[tt] < probe));
        if (cnt < K_) T = probe;
    }

    int cnt_lt = 0;
#pragma unroll
    for (int tt = 0; tt < 32; tt++)
        cnt_lt += __popcll(__ballot(rb[tt] < T));
    int m = K_ - cnt_lt;                  // how many equals (lowest j) to take

    // --- extraction: lt elements first, then first m equals in j-order ---
    int ltbase = 0, eqbase = 0;
#pragma unroll
    for (int tt = 0; tt < 32; tt++) {
        bool is_lt = rb[tt] < T;
        bool is_eq = rb[tt] == T;
        unsigned long long mlt = __ballot(is_lt);
        unsigned long long meq = __ballot(is_eq);
        int pos_lt = ltbase + lane_mbcnt(mlt);
        int pos_eq = eqbase + lane_mbcnt(meq);
        if (is_lt) {
            sj[wid][pos_lt] = tt*64 + lane;
            sr[wid][pos_lt] = rb[tt];
        } else if (is_eq && pos_eq < m) {
            sj[wid][cnt_lt + pos_eq] = tt*64 + lane;
            sr[wid][cnt_lt + pos_eq] = rb[tt];
        }
        ltbase += __popcll(mlt);
        eqbase += __popcll(meq);
    }
    __syncthreads();

    if (lane < K_) {
        float arg = __uint_as_float(sr[wid][lane]);
        topk_idx [(size_t)bi * K_ + lane] = sj[wid][lane];
        topk_dist[(size_t)bi * K_ + lane] = acoshf(arg) * inv_sqrt_c;
    }
}

// ---------------------------------------------------------------------------
// Sparse attention with bf16 K/V. One wave per (b,h,i).
// Score: lane-pair per neighbor; each lane reads 32 bf16 (half of k row slice).
// V: lane handles a dim-pair (dword bf16x2); lanes<32 do even neighbors,
// lanes>=32 odd; combined by one shfl_xor(32) pair at the end.
// ---------------------------------------------------------------------------
__global__ __launch_bounds__(256)
void attn_kernel(const float* __restrict__ q,
                 const unsigned short* __restrict__ kv,
                 const int* __restrict__ topk_idx, const float* __restrict__ topk_dist,
                 const float* __restrict__ log_tau_p, const float* __restrict__ attn_scale_p,
                 unsigned int* __restrict__ out)   // bf16 pairs
{
    int gw   = (blockIdx.x * blockDim.x + threadIdx.x) >> 6;
    int lane = threadIdx.x & 63;
    if (gw >= B_ * NH_ * N_) return;
    int b = gw / (NH_ * N_);
    int r = gw % (NH_ * N_);
    int h = r / N_;
    int i = r % N_;
    int tok = b * N_ + i;

    float tau    = fmaxf(__expf(*log_tau_p), 1e-8f);
    float ascale = *attn_scale_p;

    const int*   idxp = topk_idx  + (size_t)tok * K_;
    const float* dstp = topk_dist + (size_t)tok * K_;
    int   my_idx  = idxp[lane & 31];
    float my_dist = dstp[lane & 31];

    int jj   = lane >> 1;
    int half = lane & 1;

    // q half: 32 floats
    const float4* qp = (const float4*)(q + (size_t)tok * DIM_ + h * HD_ + half * 32);
    float4 qv[8];
#pragma unroll
    for (int u = 0; u < 8; u++) qv[u] = qp[u];

    // k half (bf16): 32 shorts = 4 x 16B
    int nb = __shfl(my_idx, jj);
    const uint4* kp = (const uint4*)(kv + (size_t)(b * N_ + nb) * KV_ + h * HD_ + half * 32);
    float dot = 0.f;
#pragma unroll
    for (int u = 0; u < 4; u++) {
        uint4 kw = kp[u];
        dot += qv[2*u].x   * bflo(kw.x) + qv[2*u].y   * bfhi(kw.x)
             + qv[2*u].z   * bflo(kw.y) + qv[2*u].w   * bfhi(kw.y)
             + qv[2*u+1].x * bflo(kw.z) + qv[2*u+1].y * bfhi(kw.z)
             + qv[2*u+1].z * bflo(kw.w) + qv[2*u+1].w * bfhi(kw.w);
    }
    dot += __shfl_xor(dot, 1);   // full dot on both lanes of the pair

    float fs = dot * 0.125f;                        // 1/sqrt(64)
    float gs = -__shfl(my_dist, jj) / tau;
    float s  = ascale * tanh_fast(fs + gs);

    // softmax over the 32 scores (each duplicated on a lane pair)
    float mx = s;
#pragma unroll
    for (int off = 32; off; off >>= 1) mx = fmaxf(mx, __shfl_xor(mx, off));
    float e  = __expf(s - mx);
    float ec = half ? 0.f : e;
#pragma unroll
    for (int off = 32; off; off >>= 1) ec += __shfl_xor(ec, off);
    float inv = 1.f / ec;

    // V phase: dim pair d2 = 2*(lane&31); lane>=32 handles odd neighbors
    int dp    = lane & 31;
    int half2 = lane >> 5;
    const unsigned int* vb = (const unsigned int*)(kv + DIM_ + h * HD_) + dp;
    float ax = 0.f, ay = 0.f;
#pragma unroll
    for (int it = 0; it < 16; it++) {
        int t2 = half2 + 2*it;
        float w  = __shfl(e, t2 * 2) * inv;
        int   nj = __shfl(my_idx, t2);
        unsigned vv = vb[(size_t)(b * N_ + nj) * (KV_/2)];
        ax += w * bflo(vv);
        ay += w * bfhi(vv);
    }
    ax += __shfl_xor(ax, 32);
    ay += __shfl_xor(ay, 32);
    if (lane < 32) {
        unsigned pck = ((unsigned)f2bf(ay) << 16) | (unsigned)f2bf(ax);
        out[(size_t)tok * (DIM_/2) + h * (HD_/2) + dp] = pck;
    }
}

// ---------------------------------------------------------------------------
extern "C" void kernel_launch(void* const* d_in, const int* in_sizes, int n_in,
                              void* d_out, int out_size, void* d_ws, size_t ws_size,
                              hipStream_t stream)
{
    const float* x          = (const float*)d_in[0];
    const float* positions  = (const float*)d_in[1];
    const float* c_p        = (const float*)d_in[2];
    const float* Wq         = (const float*)d_in[3];
    const float* bq         = (const float*)d_in[4];
    const float* Wk         = (const float*)d_in[5];
    const float* bk         = (const float*)d_in[6];
    const float* Wv         = (const float*)d_in[7];
    const float* bv         = (const float*)d_in[8];
    const float* Wo         = (const float*)d_in[9];
    const float* bo         = (const float*)d_in[10];
    const float* W1         = (const float*)d_in[11];
    const float* b1         = (const float*)d_in[12];
    const float* W2         = (const float*)d_in[13];
    const float* b2         = (const float*)d_in[14];
    const float* ln1_scale  = (const float*)d_in[15];
    const float* ln1_bias   = (const float*)d_in[16];
    const float* ln2_scale  = (const float*)d_in[17];
    const float* ln2_bias   = (const float*)d_in[18];
    const float* log_tau    = (const float*)d_in[19];
    const float* attn_scale = (const float*)d_in[20];

    char* p = (char*)d_ws;
    unsigned short* qkvWt  = (unsigned short*)p; p += (size_t)QKV_ * DIM_ * 2;   // [1536][512] bf16
    unsigned short* WoT    = (unsigned short*)p; p += (size_t)DIM_ * DIM_ * 2;   // [512][512]
    unsigned short* W1T    = (unsigned short*)p; p += (size_t)FFN_ * DIM_ * 2;   // [2048][512]
    unsigned short* W2T    = (unsigned short*)p; p += (size_t)DIM_ * FFN_ * 2;   // [512][2048]
    float*          qkv_b  = (float*)p;          p += (size_t)QKV_ * 4;
    unsigned short* xn     = (unsigned short*)p; p += (size_t)TOK_ * DIM_ * 2;   // bf16
    float*          qf     = (float*)p;          p += (size_t)TOK_ * DIM_ * 4;   // fp32 q
    unsigned short* kvb    = (unsigned short*)p; p += (size_t)TOK_ * KV_ * 2;    // bf16 k|v
    unsigned short* attn_o = (unsigned short*)p; p += (size_t)TOK_ * DIM_ * 2;   // bf16
    float*          x1     = (float*)p;          p += (size_t)TOK_ * DIM_ * 4;
    unsigned short* x2n    = (unsigned short*)p; p += (size_t)TOK_ * DIM_ * 2;
    unsigned short* hbuf   = (unsigned short*)p; p += (size_t)TOK_ * FFN_ * 2;
    float*          pos_sq = (float*)p;          p += (size_t)TOK_ * 4;
    float*          tk_d   = (float*)p;          p += (size_t)TOK_ * K_ * 4;
    int*            tk_i   = (int*)p;            p += (size_t)TOK_ * K_ * 4;

    // --- prep: all weight transposes + bias pack + pos_sq in one launch ---
    prep_kernel<<<3095, 256, 0, stream>>>(Wq, Wk, Wv, Wo, W1, W2, bq, bk, bv,
                                          qkvWt, WoT, W1T, W2T, qkv_b,
                                          positions, pos_sq);

    // --- LN1 -> bf16 ---
    layernorm_kernel<<<TOK_/4, 256, 0, stream>>>(x, ln1_scale, ln1_bias, xn);

    // --- fused QKV GEMM: q -> fp32 [tok][512]; k|v -> bf16 [tok][1024] ---
    gemm_bf16_kernel<3><<<dim3(QKV_/128, TOK_/128), 256, 0, stream>>>(
        xn, qkvWt, qkv_b, nullptr, qf, kvb, TOK_, QKV_, DIM_);

    // --- distances + top-k ---
    dist_topk_radix_kernel<<<TOK_/4, 256, 0, stream>>>(positions, pos_sq, c_p, tk_i, tk_d);

    // --- sparse attention -> bf16 ---
    attn_kernel<<<(B_*NH_*N_)/4, 256, 0, stream>>>(qf, kvb, tk_i, tk_d,
                                                   log_tau, attn_scale,
                                                   (unsigned int*)attn_o);

    // --- x1 = x + attn_o @ Wo + bo (fp32) ---
    gemm_bf16_kernel<1><<<dim3(DIM_/128, TOK_/128), 256, 0, stream>>>(
        attn_o, WoT, bo, x, x1, nullptr, TOK_, DIM_, DIM_);

    // --- LN2 -> bf16 ---
    layernorm_kernel<<<TOK_/4, 256, 0, stream>>>(x1, ln2_scale, ln2_bias, x2n);

    // --- FFN1: gelu(x2n @ W1 + b1) -> bf16 h ---
    gemm_bf16_kernel<2><<<dim3(FFN_/128, TOK_/128), 256, 0, stream>>>(
        x2n, W1T, b1, nullptr, nullptr, hbuf, TOK_, FFN_, DIM_);

    // --- FFN2: out = x1 + h @ W2 + b2 (fp32) ---
    gemm_bf16_kernel<1><<<dim3(DIM_/128, TOK_/128), 256, 0, stream>>>(
        hbuf, W2T, b2, x1, (float*)d_out, nullptr, TOK_, DIM_, FFN_);
}

// Round 6
// 291.295 us; speedup vs baseline: 2.9979x; 1.0659x over previous
//
#include <hip/hip_runtime.h>
#include <math.h>

#define B_   2
#define N_   2048
#define DIM_ 512
#define NH_  8
#define HD_  64
#define K_   32
#define PD_  16
#define TOK_ (B_*N_)     // 4096 rows
#define FFN_ 2048
#define QKV_ (3*DIM_)    // 1536
#define KV_  1024        // k|v bf16 row length

typedef __bf16 bf16x8 __attribute__((ext_vector_type(8)));
typedef float  f32x4  __attribute__((ext_vector_type(4)));

__device__ __forceinline__ unsigned short f2bf(float f) {
    unsigned int u = __float_as_uint(f);
    u = (u + 0x7fffu + ((u >> 16) & 1u)) >> 16;
    return (unsigned short)u;
}

__device__ __forceinline__ float bflo(unsigned u) { return __uint_as_float(u << 16); }
__device__ __forceinline__ float bfhi(unsigned u) { return __uint_as_float(u & 0xffff0000u); }

__device__ __forceinline__ float gelu_tanh(float x) {
    float x3 = x * x * x;
    return 0.5f * x * (1.f + tanhf(0.7978845608028654f * (x + 0.044715f * x3)));
}

__device__ __forceinline__ float tanh_fast(float x) {
    float e = __expf(2.f * x);
    return 1.f - 2.f / (e + 1.f);
}

__device__ __forceinline__ int lane_mbcnt(unsigned long long m) {
    return __builtin_amdgcn_mbcnt_hi((unsigned)(m >> 32),
           __builtin_amdgcn_mbcnt_lo((unsigned)m, 0));
}

// async global->LDS, 16B per lane. LDS dst must be wave-uniform base + lane*16.
#define GLOAD_LDS16(g, l) __builtin_amdgcn_global_load_lds(                        \
    (const __attribute__((address_space(1))) unsigned int*)(const void*)(g),       \
    (__attribute__((address_space(3))) unsigned int*)(void*)(l), 16, 0, 0)

// ---------------------------------------------------------------------------
// LayerNorm: one wave per row of 512; writes bf16.
// ---------------------------------------------------------------------------
__global__ void layernorm_kernel(const float* __restrict__ x,
                                 const float* __restrict__ scale,
                                 const float* __restrict__ bias,
                                 unsigned short* __restrict__ y)
{
    int wave = (blockIdx.x * blockDim.x + threadIdx.x) >> 6;
    int lane = threadIdx.x & 63;
    if (wave >= TOK_) return;
    const float* xr = x + (size_t)wave * DIM_;
    float v[8];
    float s = 0.f;
#pragma unroll
    for (int i = 0; i < 8; i++) { v[i] = xr[lane + i*64]; s += v[i]; }
#pragma unroll
    for (int off = 32; off; off >>= 1) s += __shfl_xor(s, off);
    float mean = s * (1.f / DIM_);
    float vs = 0.f;
#pragma unroll
    for (int i = 0; i < 8; i++) { float d = v[i] - mean; vs += d*d; }
#pragma unroll
    for (int off = 32; off; off >>= 1) vs += __shfl_xor(vs, off);
    float inv = rsqrtf(vs * (1.f / DIM_) + 1e-6f);
    unsigned short* yr = y + (size_t)wave * DIM_;
#pragma unroll
    for (int i = 0; i < 8; i++) {
        int c = lane + i*64;
        yr[c] = f2bf((v[i] - mean) * inv * scale[c] + bias[c]);
    }
}

// ---------------------------------------------------------------------------
// ONE prep kernel: 6 weight transposes (32x32 tiles) + bias3 pack + pos_sq.
// ---------------------------------------------------------------------------
__global__ void prep_kernel(const float* __restrict__ Wq, const float* __restrict__ Wk,
                            const float* __restrict__ Wv, const float* __restrict__ Wo,
                            const float* __restrict__ W1, const float* __restrict__ W2,
                            const float* __restrict__ bq, const float* __restrict__ bk,
                            const float* __restrict__ bv,
                            unsigned short* __restrict__ qkvWt,
                            unsigned short* __restrict__ WoT,
                            unsigned short* __restrict__ W1T,
                            unsigned short* __restrict__ W2T,
                            float* __restrict__ qkv_b,
                            const float* __restrict__ pos,
                            float* __restrict__ pos_sq)
{
    int id = blockIdx.x;
    if (id >= 3079) {                 // pos_sq
        int i = (id - 3079) * 256 + threadIdx.x;
        if (i < TOK_) {
            const float4* p = (const float4*)(pos + (size_t)i * PD_);
            float s = 0.f;
#pragma unroll
            for (int d = 0; d < 4; d++) {
                float4 q = p[d];
                s += q.x*q.x + q.y*q.y + q.z*q.z + q.w*q.w;
            }
            pos_sq[i] = s;
        }
        return;
    }
    if (id >= 3072) {                 // bias pack
        int i = (id - 3072) * 256 + threadIdx.x;
        if (i < DIM_)            qkv_b[i] = bq[i];
        else if (i < 2*DIM_)     qkv_b[i] = bk[i - DIM_];
        else if (i < 3*DIM_)     qkv_b[i] = bv[i - 2*DIM_];
        return;
    }

    const float* W; unsigned short* Wt; int Kd, Nw, nx, t;
    if      (id < 256)  { W = Wq; Wt = qkvWt;               Kd = 512;  Nw = 512;  nx = 16; t = id; }
    else if (id < 512)  { W = Wk; Wt = qkvWt + 512*512;     Kd = 512;  Nw = 512;  nx = 16; t = id - 256; }
    else if (id < 768)  { W = Wv; Wt = qkvWt + 2*512*512;   Kd = 512;  Nw = 512;  nx = 16; t = id - 512; }
    else if (id < 1024) { W = Wo; Wt = WoT;                 Kd = 512;  Nw = 512;  nx = 16; t = id - 768; }
    else if (id < 2048) { W = W1; Wt = W1T;                 Kd = 512;  Nw = 2048; nx = 64; t = id - 1024; }
    else                { W = W2; Wt = W2T;                 Kd = 2048; Nw = 512;  nx = 16; t = id - 2048; }

    __shared__ float tile[32][33];
    int n0 = (t % nx) * 32, k0 = (t / nx) * 32;
    int tx = threadIdx.x & 31, ty = threadIdx.x >> 5;
#pragma unroll
    for (int i = 0; i < 32; i += 8)
        tile[ty + i][tx] = W[(size_t)(k0 + ty + i) * Nw + n0 + tx];
    __syncthreads();
#pragma unroll
    for (int i = 0; i < 32; i += 8)
        Wt[(size_t)(n0 + ty + i) * Kd + k0 + tx] = f2bf(tile[tx][ty + i]);
}

// ---------------------------------------------------------------------------
// bf16 MFMA GEMM: C[M,N] = A[M,Kd] @ Bt[N,Kd]^T (+bias / +res / gelu)
// 128x128 tile, BK=32, 256 threads (4 waves 2x2), 16x16x32 bf16 MFMA.
// EPI: 0 = +bias -> fp32 ; 1 = +bias+res -> fp32 ; 2 = gelu(+bias) -> bf16
//      3 = QKV split: col<512 -> q fp32 [row][512]; col>=512 -> kv bf16 [row][1024]
// ---------------------------------------------------------------------------
template<int EPI>
__global__ __launch_bounds__(256)
void gemm_bf16_kernel(const unsigned short* __restrict__ A,
                      const unsigned short* __restrict__ Bt,
                      const float* __restrict__ bias,
                      const float* __restrict__ res,
                      float* __restrict__ Cf,
                      unsigned short* __restrict__ Cb,
                      int M, int N, int Kd)
{
    __shared__ unsigned short As[128*32];   // 8 KB
    __shared__ unsigned short Bs[128*32];   // 8 KB

    int t    = threadIdx.x;
    int lane = t & 63;
    int wid  = t >> 6;
    int wm   = wid >> 1, wn = wid & 1;

    int bm0 = blockIdx.y * 128;
    int bn0 = blockIdx.x * 128;

    int srow = t >> 2;          // 0..63
    int scol = (t & 3) * 8;     // 0,8,16,24

    const unsigned short* gA0 = A  + (size_t)(bm0 + srow)      * Kd + scol;
    const unsigned short* gA1 = A  + (size_t)(bm0 + 64 + srow) * Kd + scol;
    const unsigned short* gB0 = Bt + (size_t)(bn0 + srow)      * Kd + scol;
    const unsigned short* gB1 = Bt + (size_t)(bn0 + 64 + srow) * Kd + scol;

    unsigned short* lA0 = As + t*8;          // == (srow*32 + scol)
    unsigned short* lA1 = As + 2048 + t*8;
    unsigned short* lB0 = Bs + t*8;
    unsigned short* lB1 = Bs + 2048 + t*8;

    f32x4 acc[4][4] = {};

    int arow = wm*64 + (lane & 15);       // + mi*16
    int brow = wn*64 + (lane & 15);       // + ni*16
    int kfrag = (lane >> 4) * 8;

    for (int k0 = 0; k0 < Kd; k0 += 32) {
        GLOAD_LDS16(gA0 + k0, lA0);
        GLOAD_LDS16(gA1 + k0, lA1);
        GLOAD_LDS16(gB0 + k0, lB0);
        GLOAD_LDS16(gB1 + k0, lB1);
        __syncthreads();

        bf16x8 af[4], bf[4];
#pragma unroll
        for (int mi = 0; mi < 4; mi++)
            af[mi] = *(const bf16x8*)(As + (arow + mi*16)*32 + kfrag);
#pragma unroll
        for (int ni = 0; ni < 4; ni++)
            bf[ni] = *(const bf16x8*)(Bs + (brow + ni*16)*32 + kfrag);
#pragma unroll
        for (int mi = 0; mi < 4; mi++)
#pragma unroll
            for (int ni = 0; ni < 4; ni++)
                acc[mi][ni] = __builtin_amdgcn_mfma_f32_16x16x32_bf16(
                    af[mi], bf[ni], acc[mi][ni], 0, 0, 0);
        __syncthreads();
    }

    // epilogue: D row = (lane>>4)*4 + r, col = lane&15 within each 16x16 tile
#pragma unroll
    for (int mi = 0; mi < 4; mi++) {
#pragma unroll
        for (int ni = 0; ni < 4; ni++) {
            int col = bn0 + wn*64 + ni*16 + (lane & 15);
            float bv = bias[col];
#pragma unroll
            for (int r = 0; r < 4; r++) {
                int row = bm0 + wm*64 + mi*16 + (lane >> 4)*4 + r;
                float val = acc[mi][ni][r] + bv;
                if (EPI == 1) val += res[(size_t)row * N + col];
                if (EPI == 2) {
                    val = gelu_tanh(val);
                    Cb[(size_t)row * N + col] = f2bf(val);
                } else if (EPI == 3) {
                    if (col < DIM_) Cf[(size_t)row * DIM_ + col] = val;
                    else            Cb[(size_t)row * KV_ + (col - DIM_)] = f2bf(val);
                } else {
                    Cf[(size_t)row * N + col] = val;
                }
            }
        }
    }
}

// ---------------------------------------------------------------------------
// Poincare dist + exact top-K, split: 2 waves per row (1024 dists each,
// 16 regs/lane). Each wave radix-selects its LOCAL top-32 (by (arg,j) key
// order); union of the two local top-32s contains the global top-32.
// Merge: 64 packed u64 keys (arg_bits<<32 | j) in LDS; wave hw==0 computes
// each candidate's exact rank via 64 broadcast LDS reads + u64 compares
// (keys unique -> no tie ambiguity; == jax.lax.top_k lower-index-first).
// acosh only on the 32 winners.
// ---------------------------------------------------------------------------
__global__ __launch_bounds__(256)
void dist_topk_split_kernel(const float* __restrict__ pos, const float* __restrict__ pos_sq,
                            const float* __restrict__ c_ptr,
                            int* __restrict__ topk_idx, float* __restrict__ topk_dist)
{
    __shared__ unsigned long long cand[2][64];

    int wid  = threadIdx.x >> 6;      // 0..3
    int lane = threadIdx.x & 63;
    int rw   = wid >> 1;              // row within block
    int hw   = wid & 1;               // half within row
    int bi   = blockIdx.x * 2 + rw;   // 0..TOK_-1
    int b    = bi >> 11;              // / N_
    float c  = *c_ptr;
    float inv_sqrt_c = rsqrtf(c);

    const float4* pi4 = (const float4*)(pos + (size_t)bi * PD_);
    float4 p0 = pi4[0], p1 = pi4[1], p2 = pi4[2], p3 = pi4[3];
    float ni = pos_sq[bi];
    float omci = 1.f - c * ni;

    const float* pb  = pos + (size_t)b * N_ * PD_;
    const float* sqb = pos_sq + b * N_;
    int jbase = hw * 1024;

    unsigned rb[16];
#pragma unroll
    for (int tt = 0; tt < 16; tt++) {
        int j = jbase + tt*64 + lane;
        const float4* pj = (const float4*)(pb + (size_t)j * PD_);
        float4 q0 = pj[0], q1 = pj[1], q2 = pj[2], q3 = pj[3];
        float diff =
            (p0.x-q0.x)*(p0.x-q0.x) + (p0.y-q0.y)*(p0.y-q0.y) +
            (p0.z-q0.z)*(p0.z-q0.z) + (p0.w-q0.w)*(p0.w-q0.w) +
            (p1.x-q1.x)*(p1.x-q1.x) + (p1.y-q1.y)*(p1.y-q1.y) +
            (p1.z-q1.z)*(p1.z-q1.z) + (p1.w-q1.w)*(p1.w-q1.w) +
            (p2.x-q2.x)*(p2.x-q2.x) + (p2.y-q2.y)*(p2.y-q2.y) +
            (p2.z-q2.z)*(p2.z-q2.z) + (p2.w-q2.w)*(p2.w-q2.w) +
            (p3.x-q3.x)*(p3.x-q3.x) + (p3.y-q3.y)*(p3.y-q3.y) +
            (p3.z-q3.z)*(p3.z-q3.z) + (p3.w-q3.w)*(p3.w-q3.w);
        float den = fmaxf(omci * (1.f - c * sqb[j]), 1e-8f);
        float arg = fmaxf(1.f + 2.f * c * diff / den, 1.f + 1e-7f);
        rb[tt] = __float_as_uint(arg);   // arg >= 1.0 > 0: bits monotone in dist
    }

    // --- local radix select: T = 32nd-smallest bit pattern among this 1024 ---
    unsigned T = 0;
    for (int bit = 30; bit >= 0; --bit) {
        unsigned probe = T | (1u << bit);
        int cnt = 0;
#pragma unroll
        for (int tt = 0; tt < 16; tt++)
            cnt += __popcll(__ballot(rb[tt] < probe));
        if (cnt < K_) T = probe;
    }

    int cnt_lt = 0;
#pragma unroll
    for (int tt = 0; tt < 16; tt++)
        cnt_lt += __popcll(__ballot(rb[tt] < T));
    int m = K_ - cnt_lt;                  // equals (lowest j) to take

    // --- extraction of local top-32 as packed keys into LDS ---
    int ltbase = 0, eqbase = 0;
#pragma unroll
    for (int tt = 0; tt < 16; tt++) {
        bool is_lt = rb[tt] < T;
        bool is_eq = rb[tt] == T;
        unsigned long long mlt = __ballot(is_lt);
        unsigned long long meq = __ballot(is_eq);
        int plt = ltbase + lane_mbcnt(mlt);
        int peq = eqbase + lane_mbcnt(meq);
        unsigned long long key =
            ((unsigned long long)rb[tt] << 32) | (unsigned)(jbase + tt*64 + lane);
        if (is_lt)                 cand[rw][hw*K_ + plt] = key;
        else if (is_eq && peq < m) cand[rw][hw*K_ + cnt_lt + peq] = key;
        ltbase += __popcll(mlt);
        eqbase += __popcll(meq);
    }
    __syncthreads();

    // --- merge: exact rank of each of the 64 candidates ---
    if (hw == 0) {
        unsigned long long mykey = cand[rw][lane];
        int rank = 0;
#pragma unroll 8
        for (int M = 0; M < 64; M++)
            rank += (cand[rw][M] < mykey) ? 1 : 0;
        if (rank < K_) {
            unsigned rbv = (unsigned)(mykey >> 32);
            int      j   = (int)(mykey & 0xffffffffu);
            topk_idx [(size_t)bi * K_ + rank] = j;
            topk_dist[(size_t)bi * K_ + rank] = acoshf(__uint_as_float(rbv)) * inv_sqrt_c;
        }
    }
}

// ---------------------------------------------------------------------------
// Sparse attention with bf16 K/V. One wave per (b,h,i).
// ---------------------------------------------------------------------------
__global__ __launch_bounds__(256)
void attn_kernel(const float* __restrict__ q,
                 const unsigned short* __restrict__ kv,
                 const int* __restrict__ topk_idx, const float* __restrict__ topk_dist,
                 const float* __restrict__ log_tau_p, const float* __restrict__ attn_scale_p,
                 unsigned int* __restrict__ out)   // bf16 pairs
{
    int gw   = (blockIdx.x * blockDim.x + threadIdx.x) >> 6;
    int lane = threadIdx.x & 63;
    if (gw >= B_ * NH_ * N_) return;
    int b = gw / (NH_ * N_);
    int r = gw % (NH_ * N_);
    int h = r / N_;
    int i = r % N_;
    int tok = b * N_ + i;

    float tau    = fmaxf(__expf(*log_tau_p), 1e-8f);
    float ascale = *attn_scale_p;

    const int*   idxp = topk_idx  + (size_t)tok * K_;
    const float* dstp = topk_dist + (size_t)tok * K_;
    int   my_idx  = idxp[lane & 31];
    float my_dist = dstp[lane & 31];

    int jj   = lane >> 1;
    int half = lane & 1;

    // q half: 32 floats
    const float4* qp = (const float4*)(q + (size_t)tok * DIM_ + h * HD_ + half * 32);
    float4 qv[8];
#pragma unroll
    for (int u = 0; u < 8; u++) qv[u] = qp[u];

    // k half (bf16): 32 shorts = 4 x 16B
    int nb = __shfl(my_idx, jj);
    const uint4* kp = (const uint4*)(kv + (size_t)(b * N_ + nb) * KV_ + h * HD_ + half * 32);
    float dot = 0.f;
#pragma unroll
    for (int u = 0; u < 4; u++) {
        uint4 kw = kp[u];
        dot += qv[2*u].x   * bflo(kw.x) + qv[2*u].y   * bfhi(kw.x)
             + qv[2*u].z   * bflo(kw.y) + qv[2*u].w   * bfhi(kw.y)
             + qv[2*u+1].x * bflo(kw.z) + qv[2*u+1].y * bfhi(kw.z)
             + qv[2*u+1].z * bflo(kw.w) + qv[2*u+1].w * bfhi(kw.w);
    }
    dot += __shfl_xor(dot, 1);   // full dot on both lanes of the pair

    float fs = dot * 0.125f;                        // 1/sqrt(64)
    float gs = -__shfl(my_dist, jj) / tau;
    float s  = ascale * tanh_fast(fs + gs);

    // softmax over the 32 scores (each duplicated on a lane pair)
    float mx = s;
#pragma unroll
    for (int off = 32; off; off >>= 1) mx = fmaxf(mx, __shfl_xor(mx, off));
    float e  = __expf(s - mx);
    float ec = half ? 0.f : e;
#pragma unroll
    for (int off = 32; off; off >>= 1) ec += __shfl_xor(ec, off);
    float inv = 1.f / ec;

    // V phase: dim pair d2 = 2*(lane&31); lane>=32 handles odd neighbors
    int dp    = lane & 31;
    int half2 = lane >> 5;
    const unsigned int* vb = (const unsigned int*)(kv + DIM_ + h * HD_) + dp;
    float ax = 0.f, ay = 0.f;
#pragma unroll
    for (int it = 0; it < 16; it++) {
        int t2 = half2 + 2*it;
        float w  = __shfl(e, t2 * 2) * inv;
        int   nj = __shfl(my_idx, t2);
        unsigned vv = vb[(size_t)(b * N_ + nj) * (KV_/2)];
        ax += w * bflo(vv);
        ay += w * bfhi(vv);
    }
    ax += __shfl_xor(ax, 32);
    ay += __shfl_xor(ay, 32);
    if (lane < 32) {
        unsigned pck = ((unsigned)f2bf(ay) << 16) | (unsigned)f2bf(ax);
        out[(size_t)tok * (DIM_/2) + h * (HD_/2) + dp] = pck;
    }
}

// ---------------------------------------------------------------------------
extern "C" void kernel_launch(void* const* d_in, const int* in_sizes, int n_in,
                              void* d_out, int out_size, void* d_ws, size_t ws_size,
                              hipStream_t stream)
{
    const float* x          = (const float*)d_in[0];
    const float* positions  = (const float*)d_in[1];
    const float* c_p        = (const float*)d_in[2];
    const float* Wq         = (const float*)d_in[3];
    const float* bq         = (const float*)d_in[4];
    const float* Wk         = (const float*)d_in[5];
    const float* bk         = (const float*)d_in[6];
    const float* Wv         = (const float*)d_in[7];
    const float* bv         = (const float*)d_in[8];
    const float* Wo         = (const float*)d_in[9];
    const float* bo         = (const float*)d_in[10];
    const float* W1         = (const float*)d_in[11];
    const float* b1         = (const float*)d_in[12];
    const float* W2         = (const float*)d_in[13];
    const float* b2         = (const float*)d_in[14];
    const float* ln1_scale  = (const float*)d_in[15];
    const float* ln1_bias   = (const float*)d_in[16];
    const float* ln2_scale  = (const float*)d_in[17];
    const float* ln2_bias   = (const float*)d_in[18];
    const float* log_tau    = (const float*)d_in[19];
    const float* attn_scale = (const float*)d_in[20];

    char* p = (char*)d_ws;
    unsigned short* qkvWt  = (unsigned short*)p; p += (size_t)QKV_ * DIM_ * 2;   // [1536][512] bf16
    unsigned short* WoT    = (unsigned short*)p; p += (size_t)DIM_ * DIM_ * 2;   // [512][512]
    unsigned short* W1T    = (unsigned short*)p; p += (size_t)FFN_ * DIM_ * 2;   // [2048][512]
    unsigned short* W2T    = (unsigned short*)p; p += (size_t)DIM_ * FFN_ * 2;   // [512][2048]
    float*          qkv_b  = (float*)p;          p += (size_t)QKV_ * 4;
    unsigned short* xn     = (unsigned short*)p; p += (size_t)TOK_ * DIM_ * 2;   // bf16
    float*          qf     = (float*)p;          p += (size_t)TOK_ * DIM_ * 4;   // fp32 q
    unsigned short* kvb    = (unsigned short*)p; p += (size_t)TOK_ * KV_ * 2;    // bf16 k|v
    unsigned short* attn_o = (unsigned short*)p; p += (size_t)TOK_ * DIM_ * 2;   // bf16
    float*          x1     = (float*)p;          p += (size_t)TOK_ * DIM_ * 4;
    unsigned short* x2n    = (unsigned short*)p; p += (size_t)TOK_ * DIM_ * 2;
    unsigned short* hbuf   = (unsigned short*)p; p += (size_t)TOK_ * FFN_ * 2;
    float*          pos_sq = (float*)p;          p += (size_t)TOK_ * 4;
    float*          tk_d   = (float*)p;          p += (size_t)TOK_ * K_ * 4;
    int*            tk_i   = (int*)p;            p += (size_t)TOK_ * K_ * 4;

    // --- prep: all weight transposes + bias pack + pos_sq in one launch ---
    prep_kernel<<<3095, 256, 0, stream>>>(Wq, Wk, Wv, Wo, W1, W2, bq, bk, bv,
                                          qkvWt, WoT, W1T, W2T, qkv_b,
                                          positions, pos_sq);

    // --- LN1 -> bf16 ---
    layernorm_kernel<<<TOK_/4, 256, 0, stream>>>(x, ln1_scale, ln1_bias, xn);

    // --- fused QKV GEMM: q -> fp32 [tok][512]; k|v -> bf16 [tok][1024] ---
    gemm_bf16_kernel<3><<<dim3(QKV_/128, TOK_/128), 256, 0, stream>>>(
        xn, qkvWt, qkv_b, nullptr, qf, kvb, TOK_, QKV_, DIM_);

    // --- distances + top-k (2 waves/row) ---
    dist_topk_split_kernel<<<TOK_/2, 256, 0, stream>>>(positions, pos_sq, c_p, tk_i, tk_d);

    // --- sparse attention -> bf16 ---
    attn_kernel<<<(B_*NH_*N_)/4, 256, 0, stream>>>(qf, kvb, tk_i, tk_d,
                                                   log_tau, attn_scale,
                                                   (unsigned int*)attn_o);

    // --- x1 = x + attn_o @ Wo + bo (fp32) ---
    gemm_bf16_kernel<1><<<dim3(DIM_/128, TOK_/128), 256, 0, stream>>>(
        attn_o, WoT, bo, x, x1, nullptr, TOK_, DIM_, DIM_);

    // --- LN2 -> bf16 ---
    layernorm_kernel<<<TOK_/4, 256, 0, stream>>>(x1, ln2_scale, ln2_bias, x2n);

    // --- FFN1: gelu(x2n @ W1 + b1) -> bf16 h ---
    gemm_bf16_kernel<2><<<dim3(FFN_/128, TOK_/128), 256, 0, stream>>>(
        x2n, W1T, b1, nullptr, nullptr, hbuf, TOK_, FFN_, DIM_);

    // --- FFN2: out = x1 + h @ W2 + b2 (fp32) ---
    gemm_bf16_kernel<1><<<dim3(DIM_/128, TOK_/128), 256, 0, stream>>>(
        hbuf, W2T, b2, x1, (float*)d_out, nullptr, TOK_, DIM_, FFN_);
}

// Round 7
// 273.892 us; speedup vs baseline: 3.1884x; 1.0635x over previous
//
#include <hip/hip_runtime.h>
#include <math.h>

#define B_   2
#define N_   2048
#define DIM_ 512
#define NH_  8
#define HD_  64
#define K_   32
#define PD_  16
#define TOK_ (B_*N_)     // 4096 rows
#define FFN_ 2048
#define QKV_ (3*DIM_)    // 1536
#define KV_  1024        // k|v bf16 row length

typedef __bf16 bf16x8 __attribute__((ext_vector_type(8)));
typedef float  f32x4  __attribute__((ext_vector_type(4)));

__device__ __forceinline__ unsigned short f2bf(float f) {
    unsigned int u = __float_as_uint(f);
    u = (u + 0x7fffu + ((u >> 16) & 1u)) >> 16;
    return (unsigned short)u;
}

__device__ __forceinline__ float bflo(unsigned u) { return __uint_as_float(u << 16); }
__device__ __forceinline__ float bfhi(unsigned u) { return __uint_as_float(u & 0xffff0000u); }

__device__ __forceinline__ float gelu_tanh(float x) {
    float x3 = x * x * x;
    return 0.5f * x * (1.f + tanhf(0.7978845608028654f * (x + 0.044715f * x3)));
}

__device__ __forceinline__ float tanh_fast(float x) {
    float e = __expf(2.f * x);
    return 1.f - 2.f / (e + 1.f);
}

__device__ __forceinline__ int lane_mbcnt(unsigned long long m) {
    return __builtin_amdgcn_mbcnt_hi((unsigned)(m >> 32),
           __builtin_amdgcn_mbcnt_lo((unsigned)m, 0));
}

// async global->LDS, 16B per lane. LDS dst must be wave-uniform base + lane*16.
#define GLOAD_LDS16(g, l) __builtin_amdgcn_global_load_lds(                        \
    (const __attribute__((address_space(1))) unsigned int*)(const void*)(g),       \
    (__attribute__((address_space(3))) unsigned int*)(void*)(l), 16, 0, 0)

// ---------------------------------------------------------------------------
// LayerNorm: one wave per row of 512; writes bf16.
// ---------------------------------------------------------------------------
__global__ void layernorm_kernel(const float* __restrict__ x,
                                 const float* __restrict__ scale,
                                 const float* __restrict__ bias,
                                 unsigned short* __restrict__ y)
{
    int wave = (blockIdx.x * blockDim.x + threadIdx.x) >> 6;
    int lane = threadIdx.x & 63;
    if (wave >= TOK_) return;
    const float* xr = x + (size_t)wave * DIM_;
    float v[8];
    float s = 0.f;
#pragma unroll
    for (int i = 0; i < 8; i++) { v[i] = xr[lane + i*64]; s += v[i]; }
#pragma unroll
    for (int off = 32; off; off >>= 1) s += __shfl_xor(s, off);
    float mean = s * (1.f / DIM_);
    float vs = 0.f;
#pragma unroll
    for (int i = 0; i < 8; i++) { float d = v[i] - mean; vs += d*d; }
#pragma unroll
    for (int off = 32; off; off >>= 1) vs += __shfl_xor(vs, off);
    float inv = rsqrtf(vs * (1.f / DIM_) + 1e-6f);
    unsigned short* yr = y + (size_t)wave * DIM_;
#pragma unroll
    for (int i = 0; i < 8; i++) {
        int c = lane + i*64;
        yr[c] = f2bf((v[i] - mean) * inv * scale[c] + bias[c]);
    }
}

// ---------------------------------------------------------------------------
// ONE prep kernel: 6 weight transposes (32x32 tiles) + bias3 pack + pos_sq.
// ---------------------------------------------------------------------------
__global__ void prep_kernel(const float* __restrict__ Wq, const float* __restrict__ Wk,
                            const float* __restrict__ Wv, const float* __restrict__ Wo,
                            const float* __restrict__ W1, const float* __restrict__ W2,
                            const float* __restrict__ bq, const float* __restrict__ bk,
                            const float* __restrict__ bv,
                            unsigned short* __restrict__ qkvWt,
                            unsigned short* __restrict__ WoT,
                            unsigned short* __restrict__ W1T,
                            unsigned short* __restrict__ W2T,
                            float* __restrict__ qkv_b,
                            const float* __restrict__ pos,
                            float* __restrict__ pos_sq)
{
    int id = blockIdx.x;
    if (id >= 3079) {                 // pos_sq
        int i = (id - 3079) * 256 + threadIdx.x;
        if (i < TOK_) {
            const float4* p = (const float4*)(pos + (size_t)i * PD_);
            float s = 0.f;
#pragma unroll
            for (int d = 0; d < 4; d++) {
                float4 q = p[d];
                s += q.x*q.x + q.y*q.y + q.z*q.z + q.w*q.w;
            }
            pos_sq[i] = s;
        }
        return;
    }
    if (id >= 3072) {                 // bias pack
        int i = (id - 3072) * 256 + threadIdx.x;
        if (i < DIM_)            qkv_b[i] = bq[i];
        else if (i < 2*DIM_)     qkv_b[i] = bk[i - DIM_];
        else if (i < 3*DIM_)     qkv_b[i] = bv[i - 2*DIM_];
        return;
    }

    const float* W; unsigned short* Wt; int Kd, Nw, nx, t;
    if      (id < 256)  { W = Wq; Wt = qkvWt;               Kd = 512;  Nw = 512;  nx = 16; t = id; }
    else if (id < 512)  { W = Wk; Wt = qkvWt + 512*512;     Kd = 512;  Nw = 512;  nx = 16; t = id - 256; }
    else if (id < 768)  { W = Wv; Wt = qkvWt + 2*512*512;   Kd = 512;  Nw = 512;  nx = 16; t = id - 512; }
    else if (id < 1024) { W = Wo; Wt = WoT;                 Kd = 512;  Nw = 512;  nx = 16; t = id - 768; }
    else if (id < 2048) { W = W1; Wt = W1T;                 Kd = 512;  Nw = 2048; nx = 64; t = id - 1024; }
    else                { W = W2; Wt = W2T;                 Kd = 2048; Nw = 512;  nx = 16; t = id - 2048; }

    __shared__ float tile[32][33];
    int n0 = (t % nx) * 32, k0 = (t / nx) * 32;
    int tx = threadIdx.x & 31, ty = threadIdx.x >> 5;
#pragma unroll
    for (int i = 0; i < 32; i += 8)
        tile[ty + i][tx] = W[(size_t)(k0 + ty + i) * Nw + n0 + tx];
    __syncthreads();
#pragma unroll
    for (int i = 0; i < 32; i += 8)
        Wt[(size_t)(n0 + ty + i) * Kd + k0 + tx] = f2bf(tile[tx][ty + i]);
}

// ---------------------------------------------------------------------------
// bf16 MFMA GEMM: C[M,N] = A[M,Kd] @ Bt[N,Kd]^T (+bias / +res / gelu)
// Templated tile BM x BN (128 or 64), BK=32, 256 threads (4 waves 2x2).
// LDS chunk-swizzle: LDS[row][c] holds global 16B-chunk c ^ ((row>>1)&3)
// -> fragment reads spread over all bank groups (2-way aliasing = free),
//    staging stays lane-ordered contiguous (global_load_lds constraint).
// EPI: 0 = +bias -> fp32 ; 1 = +bias+res -> fp32 ; 2 = gelu(+bias) -> bf16
//      3 = QKV split: col<512 -> q fp32 [row][512]; col>=512 -> kv bf16 [row][1024]
// ---------------------------------------------------------------------------
template<int EPI, int BM, int BN>
__global__ __launch_bounds__(256)
void gemm_bf16_kernel(const unsigned short* __restrict__ A,
                      const unsigned short* __restrict__ Bt,
                      const float* __restrict__ bias,
                      const float* __restrict__ res,
                      float* __restrict__ Cf,
                      unsigned short* __restrict__ Cb,
                      int M, int N, int Kd)
{
    constexpr int WM = BM / 2;     // wave tile m
    constexpr int WN = BN / 2;
    constexpr int FM = WM / 16;    // 16x16 frags per wave (m)
    constexpr int FN = WN / 16;

    __shared__ unsigned short As[BM*32];
    __shared__ unsigned short Bs[BN*32];

    int t    = threadIdx.x;
    int lane = t & 63;
    int wid  = t >> 6;
    int wm   = wid >> 1, wn = wid & 1;

    int bm0 = blockIdx.y * BM;
    int bn0 = blockIdx.x * BN;

    f32x4 acc[FM][FN] = {};

    int kc    = lane >> 4;               // fragment k-chunk 0..3
    int rlo   = lane & 15;

    for (int k0 = 0; k0 < Kd; k0 += 32) {
        // stage A tile
#pragma unroll
        for (int l = 0; l < BM/64; l++) {
            int idx = l*256 + t;
            int row = idx >> 2;
            int gc  = (idx & 3) ^ ((row >> 1) & 3);
            GLOAD_LDS16(A + (size_t)(bm0 + row) * Kd + k0 + gc*8, As + idx*8);
        }
        // stage B tile
#pragma unroll
        for (int l = 0; l < BN/64; l++) {
            int idx = l*256 + t;
            int row = idx >> 2;
            int gc  = (idx & 3) ^ ((row >> 1) & 3);
            GLOAD_LDS16(Bt + (size_t)(bn0 + row) * Kd + k0 + gc*8, Bs + idx*8);
        }
        __syncthreads();

        bf16x8 af[FM], bf[FN];
#pragma unroll
        for (int mi = 0; mi < FM; mi++) {
            int r = wm*WM + mi*16 + rlo;
            af[mi] = *(const bf16x8*)(As + r*32 + (kc ^ ((r>>1)&3))*8);
        }
#pragma unroll
        for (int ni = 0; ni < FN; ni++) {
            int r = wn*WN + ni*16 + rlo;
            bf[ni] = *(const bf16x8*)(Bs + r*32 + (kc ^ ((r>>1)&3))*8);
        }
#pragma unroll
        for (int mi = 0; mi < FM; mi++)
#pragma unroll
            for (int ni = 0; ni < FN; ni++)
                acc[mi][ni] = __builtin_amdgcn_mfma_f32_16x16x32_bf16(
                    af[mi], bf[ni], acc[mi][ni], 0, 0, 0);
        __syncthreads();
    }

    // epilogue: D row = (lane>>4)*4 + r, col = lane&15 within each 16x16 tile
#pragma unroll
    for (int mi = 0; mi < FM; mi++) {
#pragma unroll
        for (int ni = 0; ni < FN; ni++) {
            int col = bn0 + wn*WN + ni*16 + rlo;
            float bv = bias[col];
#pragma unroll
            for (int r = 0; r < 4; r++) {
                int row = bm0 + wm*WM + mi*16 + kc*4 + r;
                float val = acc[mi][ni][r] + bv;
                if (EPI == 1) val += res[(size_t)row * N + col];
                if (EPI == 2) {
                    val = gelu_tanh(val);
                    Cb[(size_t)row * N + col] = f2bf(val);
                } else if (EPI == 3) {
                    if (col < DIM_) Cf[(size_t)row * DIM_ + col] = val;
                    else            Cb[(size_t)row * KV_ + (col - DIM_)] = f2bf(val);
                } else {
                    Cf[(size_t)row * N + col] = val;
                }
            }
        }
    }
}

// ---------------------------------------------------------------------------
// Poincare dist + exact top-K, split: 2 waves per row (1024 dists each).
// Local radix-select top-32 per wave; merge 64 candidates by exact rank.
// ---------------------------------------------------------------------------
__global__ __launch_bounds__(256)
void dist_topk_split_kernel(const float* __restrict__ pos, const float* __restrict__ pos_sq,
                            const float* __restrict__ c_ptr,
                            int* __restrict__ topk_idx, float* __restrict__ topk_dist)
{
    __shared__ unsigned long long cand[2][64];

    int wid  = threadIdx.x >> 6;      // 0..3
    int lane = threadIdx.x & 63;
    int rw   = wid >> 1;              // row within block
    int hw   = wid & 1;               // half within row
    int bi   = blockIdx.x * 2 + rw;   // 0..TOK_-1
    int b    = bi >> 11;              // / N_
    float c  = *c_ptr;
    float inv_sqrt_c = rsqrtf(c);

    const float4* pi4 = (const float4*)(pos + (size_t)bi * PD_);
    float4 p0 = pi4[0], p1 = pi4[1], p2 = pi4[2], p3 = pi4[3];
    float ni = pos_sq[bi];
    float omci = 1.f - c * ni;

    const float* pb  = pos + (size_t)b * N_ * PD_;
    const float* sqb = pos_sq + b * N_;
    int jbase = hw * 1024;

    unsigned rb[16];
#pragma unroll
    for (int tt = 0; tt < 16; tt++) {
        int j = jbase + tt*64 + lane;
        const float4* pj = (const float4*)(pb + (size_t)j * PD_);
        float4 q0 = pj[0], q1 = pj[1], q2 = pj[2], q3 = pj[3];
        float diff =
            (p0.x-q0.x)*(p0.x-q0.x) + (p0.y-q0.y)*(p0.y-q0.y) +
            (p0.z-q0.z)*(p0.z-q0.z) + (p0.w-q0.w)*(p0.w-q0.w) +
            (p1.x-q1.x)*(p1.x-q1.x) + (p1.y-q1.y)*(p1.y-q1.y) +
            (p1.z-q1.z)*(p1.z-q1.z) + (p1.w-q1.w)*(p1.w-q1.w) +
            (p2.x-q2.x)*(p2.x-q2.x) + (p2.y-q2.y)*(p2.y-q2.y) +
            (p2.z-q2.z)*(p2.z-q2.z) + (p2.w-q2.w)*(p2.w-q2.w) +
            (p3.x-q3.x)*(p3.x-q3.x) + (p3.y-q3.y)*(p3.y-q3.y) +
            (p3.z-q3.z)*(p3.z-q3.z) + (p3.w-q3.w)*(p3.w-q3.w);
        float den = fmaxf(omci * (1.f - c * sqb[j]), 1e-8f);
        float arg = fmaxf(1.f + 2.f * c * diff / den, 1.f + 1e-7f);
        rb[tt] = __float_as_uint(arg);   // arg >= 1.0 > 0: bits monotone in dist
    }

    // --- local radix select: T = 32nd-smallest bit pattern among this 1024 ---
    unsigned T = 0;
    for (int bit = 30; bit >= 0; --bit) {
        unsigned probe = T | (1u << bit);
        int cnt = 0;
#pragma unroll
        for (int tt = 0; tt < 16; tt++)
            cnt += __popcll(__ballot(rb[tt] < probe));
        if (cnt < K_) T = probe;
    }

    int cnt_lt = 0;
#pragma unroll
    for (int tt = 0; tt < 16; tt++)
        cnt_lt += __popcll(__ballot(rb[tt] < T));
    int m = K_ - cnt_lt;                  // equals (lowest j) to take

    // --- extraction of local top-32 as packed keys into LDS ---
    int ltbase = 0, eqbase = 0;
#pragma unroll
    for (int tt = 0; tt < 16; tt++) {
        bool is_lt = rb[tt] < T;
        bool is_eq = rb[tt] == T;
        unsigned long long mlt = __ballot(is_lt);
        unsigned long long meq = __ballot(is_eq);
        int plt = ltbase + lane_mbcnt(mlt);
        int peq = eqbase + lane_mbcnt(meq);
        unsigned long long key =
            ((unsigned long long)rb[tt] << 32) | (unsigned)(jbase + tt*64 + lane);
        if (is_lt)                 cand[rw][hw*K_ + plt] = key;
        else if (is_eq && peq < m) cand[rw][hw*K_ + cnt_lt + peq] = key;
        ltbase += __popcll(mlt);
        eqbase += __popcll(meq);
    }
    __syncthreads();

    // --- merge: exact rank of each of the 64 candidates ---
    if (hw == 0) {
        unsigned long long mykey = cand[rw][lane];
        int rank = 0;
#pragma unroll 8
        for (int M = 0; M < 64; M++)
            rank += (cand[rw][M] < mykey) ? 1 : 0;
        if (rank < K_) {
            unsigned rbv = (unsigned)(mykey >> 32);
            int      j   = (int)(mykey & 0xffffffffu);
            topk_idx [(size_t)bi * K_ + rank] = j;
            topk_dist[(size_t)bi * K_ + rank] = acoshf(__uint_as_float(rbv)) * inv_sqrt_c;
        }
    }
}

// ---------------------------------------------------------------------------
// Sparse attention with bf16 K/V. One wave per (b,h,i).
// ---------------------------------------------------------------------------
__global__ __launch_bounds__(256)
void attn_kernel(const float* __restrict__ q,
                 const unsigned short* __restrict__ kv,
                 const int* __restrict__ topk_idx, const float* __restrict__ topk_dist,
                 const float* __restrict__ log_tau_p, const float* __restrict__ attn_scale_p,
                 unsigned int* __restrict__ out)   // bf16 pairs
{
    int gw   = (blockIdx.x * blockDim.x + threadIdx.x) >> 6;
    int lane = threadIdx.x & 63;
    if (gw >= B_ * NH_ * N_) return;
    int b = gw / (NH_ * N_);
    int r = gw % (NH_ * N_);
    int h = r / N_;
    int i = r % N_;
    int tok = b * N_ + i;

    float tau    = fmaxf(__expf(*log_tau_p), 1e-8f);
    float ascale = *attn_scale_p;

    const int*   idxp = topk_idx  + (size_t)tok * K_;
    const float* dstp = topk_dist + (size_t)tok * K_;
    int   my_idx  = idxp[lane & 31];
    float my_dist = dstp[lane & 31];

    int jj   = lane >> 1;
    int half = lane & 1;

    // q half: 32 floats
    const float4* qp = (const float4*)(q + (size_t)tok * DIM_ + h * HD_ + half * 32);
    float4 qv[8];
#pragma unroll
    for (int u = 0; u < 8; u++) qv[u] = qp[u];

    // k half (bf16): 32 shorts = 4 x 16B
    int nb = __shfl(my_idx, jj);
    const uint4* kp = (const uint4*)(kv + (size_t)(b * N_ + nb) * KV_ + h * HD_ + half * 32);
    float dot = 0.f;
#pragma unroll
    for (int u = 0; u < 4; u++) {
        uint4 kw = kp[u];
        dot += qv[2*u].x   * bflo(kw.x) + qv[2*u].y   * bfhi(kw.x)
             + qv[2*u].z   * bflo(kw.y) + qv[2*u].w   * bfhi(kw.y)
             + qv[2*u+1].x * bflo(kw.z) + qv[2*u+1].y * bfhi(kw.z)
             + qv[2*u+1].z * bflo(kw.w) + qv[2*u+1].w * bfhi(kw.w);
    }
    dot += __shfl_xor(dot, 1);   // full dot on both lanes of the pair

    float fs = dot * 0.125f;                        // 1/sqrt(64)
    float gs = -__shfl(my_dist, jj) / tau;
    float s  = ascale * tanh_fast(fs + gs);

    // softmax over the 32 scores (each duplicated on a lane pair)
    float mx = s;
#pragma unroll
    for (int off = 32; off; off >>= 1) mx = fmaxf(mx, __shfl_xor(mx, off));
    float e  = __expf(s - mx);
    float ec = half ? 0.f : e;
#pragma unroll
    for (int off = 32; off; off >>= 1) ec += __shfl_xor(ec, off);
    float inv = 1.f / ec;

    // V phase: dim pair d2 = 2*(lane&31); lane>=32 handles odd neighbors
    int dp    = lane & 31;
    int half2 = lane >> 5;
    const unsigned int* vb = (const unsigned int*)(kv + DIM_ + h * HD_) + dp;
    float ax = 0.f, ay = 0.f;
#pragma unroll
    for (int it = 0; it < 16; it++) {
        int t2 = half2 + 2*it;
        float w  = __shfl(e, t2 * 2) * inv;
        int   nj = __shfl(my_idx, t2);
        unsigned vv = vb[(size_t)(b * N_ + nj) * (KV_/2)];
        ax += w * bflo(vv);
        ay += w * bfhi(vv);
    }
    ax += __shfl_xor(ax, 32);
    ay += __shfl_xor(ay, 32);
    if (lane < 32) {
        unsigned pck = ((unsigned)f2bf(ay) << 16) | (unsigned)f2bf(ax);
        out[(size_t)tok * (DIM_/2) + h * (HD_/2) + dp] = pck;
    }
}

// ---------------------------------------------------------------------------
extern "C" void kernel_launch(void* const* d_in, const int* in_sizes, int n_in,
                              void* d_out, int out_size, void* d_ws, size_t ws_size,
                              hipStream_t stream)
{
    const float* x          = (const float*)d_in[0];
    const float* positions  = (const float*)d_in[1];
    const float* c_p        = (const float*)d_in[2];
    const float* Wq         = (const float*)d_in[3];
    const float* bq         = (const float*)d_in[4];
    const float* Wk         = (const float*)d_in[5];
    const float* bk         = (const float*)d_in[6];
    const float* Wv         = (const float*)d_in[7];
    const float* bv         = (const float*)d_in[8];
    const float* Wo         = (const float*)d_in[9];
    const float* bo         = (const float*)d_in[10];
    const float* W1         = (const float*)d_in[11];
    const float* b1         = (const float*)d_in[12];
    const float* W2         = (const float*)d_in[13];
    const float* b2         = (const float*)d_in[14];
    const float* ln1_scale  = (const float*)d_in[15];
    const float* ln1_bias   = (const float*)d_in[16];
    const float* ln2_scale  = (const float*)d_in[17];
    const float* ln2_bias   = (const float*)d_in[18];
    const float* log_tau    = (const float*)d_in[19];
    const float* attn_scale = (const float*)d_in[20];

    char* p = (char*)d_ws;
    unsigned short* qkvWt  = (unsigned short*)p; p += (size_t)QKV_ * DIM_ * 2;   // [1536][512] bf16
    unsigned short* WoT    = (unsigned short*)p; p += (size_t)DIM_ * DIM_ * 2;   // [512][512]
    unsigned short* W1T    = (unsigned short*)p; p += (size_t)FFN_ * DIM_ * 2;   // [2048][512]
    unsigned short* W2T    = (unsigned short*)p; p += (size_t)DIM_ * FFN_ * 2;   // [512][2048]
    float*          qkv_b  = (float*)p;          p += (size_t)QKV_ * 4;
    unsigned short* xn     = (unsigned short*)p; p += (size_t)TOK_ * DIM_ * 2;   // bf16
    float*          qf     = (float*)p;          p += (size_t)TOK_ * DIM_ * 4;   // fp32 q
    unsigned short* kvb    = (unsigned short*)p; p += (size_t)TOK_ * KV_ * 2;    // bf16 k|v
    unsigned short* attn_o = (unsigned short*)p; p += (size_t)TOK_ * DIM_ * 2;   // bf16
    float*          x1     = (float*)p;          p += (size_t)TOK_ * DIM_ * 4;
    unsigned short* x2n    = (unsigned short*)p; p += (size_t)TOK_ * DIM_ * 2;
    unsigned short* hbuf   = (unsigned short*)p; p += (size_t)TOK_ * FFN_ * 2;
    float*          pos_sq = (float*)p;          p += (size_t)TOK_ * 4;
    float*          tk_d   = (float*)p;          p += (size_t)TOK_ * K_ * 4;
    int*            tk_i   = (int*)p;            p += (size_t)TOK_ * K_ * 4;

    // --- prep: all weight transposes + bias pack + pos_sq in one launch ---
    prep_kernel<<<3095, 256, 0, stream>>>(Wq, Wk, Wv, Wo, W1, W2, bq, bk, bv,
                                          qkvWt, WoT, W1T, W2T, qkv_b,
                                          positions, pos_sq);

    // --- LN1 -> bf16 ---
    layernorm_kernel<<<TOK_/4, 256, 0, stream>>>(x, ln1_scale, ln1_bias, xn);

    // --- fused QKV GEMM: q -> fp32 [tok][512]; k|v -> bf16 [tok][1024] ---
    gemm_bf16_kernel<3,128,128><<<dim3(QKV_/128, TOK_/128), 256, 0, stream>>>(
        xn, qkvWt, qkv_b, nullptr, qf, kvb, TOK_, QKV_, DIM_);

    // --- distances + top-k (2 waves/row) ---
    dist_topk_split_kernel<<<TOK_/2, 256, 0, stream>>>(positions, pos_sq, c_p, tk_i, tk_d);

    // --- sparse attention -> bf16 ---
    attn_kernel<<<(B_*NH_*N_)/4, 256, 0, stream>>>(qf, kvb, tk_i, tk_d,
                                                   log_tau, attn_scale,
                                                   (unsigned int*)attn_o);

    // --- x1 = x + attn_o @ Wo + bo (fp32), 64x64 tiles -> 512 blocks ---
    gemm_bf16_kernel<1,64,64><<<dim3(DIM_/64, TOK_/64), 256, 0, stream>>>(
        attn_o, WoT, bo, x, x1, nullptr, TOK_, DIM_, DIM_);

    // --- LN2 -> bf16 ---
    layernorm_kernel<<<TOK_/4, 256, 0, stream>>>(x1, ln2_scale, ln2_bias, x2n);

    // --- FFN1: gelu(x2n @ W1 + b1) -> bf16 h, 128x128 -> 512 blocks ---
    gemm_bf16_kernel<2,128,128><<<dim3(FFN_/128, TOK_/128), 256, 0, stream>>>(
        x2n, W1T, b1, nullptr, nullptr, hbuf, TOK_, FFN_, DIM_);

    // --- FFN2: out = x1 + h @ W2 + b2 (fp32), 64x64 tiles -> 512 blocks ---
    gemm_bf16_kernel<1,64,64><<<dim3(DIM_/64, TOK_/64), 256, 0, stream>>>(
        hbuf, W2T, b2, x1, (float*)d_out, nullptr, TOK_, DIM_, FFN_);
}